// Round 8
// baseline (613.154 us; speedup 1.0000x reference)
//
#include <hip/hip_runtime.h>
#include <hip/hip_bf16.h>
#include <math.h>

// GAT x3 on N=100000 nodes, E=1600000 edges (+ self loops).
// Round 13: cache hygiene. z6 is L2-miss-BW bound (182MB FETCH @2.6TB/s =
// ~70us of its 91us): the 47MB zb write stream write-allocates in L2 and
// evicts the 8MB hp gather table (20% observed hit rate). Fixes:
//  - z6: non-temporal zb stores + nt srt loads; 8-edge phase-B unroll
//    (8 gathers in flight) for MLP. FMA order unchanged -> same numerics.
//  - agg4: nt srt loads, nt agg RMW, 8-edge unroll (xw stays cached).
//  - CSR build: nt for edst/esrc/ebuf streams.
// (R12: conflict-free column-major sW; R11: dsp shfl-tree; R10: fused
// weights in LDS; R9: feature12 LDS-B; R8: bucketed CSR build.)

#define NN 100000
#define NE 1600000
#define NT (NE + NN)
#define FIN 50
#define HID 40
#define COUT 121

#define NB 128           // buckets
#define NPB 782          // nodes per bucket (128*782 = 100096 >= NN)
#define EPB 8192         // edges per bin block

typedef __attribute__((ext_vector_type(8))) short bf16x8;
typedef __attribute__((ext_vector_type(4))) float f32x4;

__device__ __forceinline__ float lrelu(float x) { return fmaxf(x, 0.2f * x); }
__device__ __forceinline__ float elu1(float x)  { return x > 0.f ? x : __expf(x) - 1.f; }

// ---------------- bucketed CSR build ----------------
__global__ __launch_bounds__(256)
void zero_bcnt_kernel(int* __restrict__ bcnt) {
    int t = threadIdx.x;
    if (t < NB) bcnt[t] = 0;
}

__global__ __launch_bounds__(256)
void bin_count_kernel(const int* __restrict__ edst, int* __restrict__ bcnt) {
    __shared__ int h[NB];
    int t = threadIdx.x;
    if (t < NB) h[t] = 0;
    __syncthreads();
    int e0 = blockIdx.x * EPB;
    for (int q = 0; q < EPB; q += 256) {
        int e = e0 + q + t;
        if (e < NE) atomicAdd(&h[__builtin_nontemporal_load(&edst[e]) / NPB], 1);
    }
    __syncthreads();
    if (t < NB && h[t]) atomicAdd(&bcnt[t], h[t]);
}

__global__ __launch_bounds__(256)
void bin_scan_kernel(const int* __restrict__ bcnt, int* __restrict__ boff,
                     int* __restrict__ bcur) {
    __shared__ int s[NB];
    int t = threadIdx.x;
    if (t < NB) s[t] = bcnt[t];
    __syncthreads();
    if (t == 0) {
        int run = 0;
        for (int i = 0; i < NB; i++) { int c = s[i]; s[i] = run; run += c; }
        boff[NB] = run;   // == NE
    }
    __syncthreads();
    if (t < NB) { boff[t] = s[t]; bcur[t] = s[t]; }
}

// Each block claims a contiguous chunk per bucket, then writes packed records
// src | (dst_in_bucket << 17) into its exclusive chunk (dense, short window).
__global__ __launch_bounds__(256)
void bin_place_kernel(const int* __restrict__ esrc, const int* __restrict__ edst,
                      int* __restrict__ bcur, int* __restrict__ ebuf) {
    __shared__ int h[NB], base[NB], lcur[NB];
    int t = threadIdx.x;
    if (t < NB) h[t] = 0;
    __syncthreads();
    int e0 = blockIdx.x * EPB;
    for (int q = 0; q < EPB; q += 256) {
        int e = e0 + q + t;
        if (e < NE) atomicAdd(&h[__builtin_nontemporal_load(&edst[e]) / NPB], 1);
    }
    __syncthreads();
    if (t < NB) {
        int c = h[t];
        base[t] = c ? atomicAdd(&bcur[t], c) : 0;
        lcur[t] = 0;
    }
    __syncthreads();
    for (int q = 0; q < EPB; q += 256) {
        int e = e0 + q + t;
        if (e < NE) {
            int d = __builtin_nontemporal_load(&edst[e]);
            int s = __builtin_nontemporal_load(&esrc[e]);
            int b = d / NPB;
            int r = atomicAdd(&lcur[b], 1);
            __builtin_nontemporal_store(s | ((d - b * NPB) << 17), &ebuf[base[b] + r]);
        }
    }
}

// One block per bucket: per-node degree via LDS histogram.
__global__ __launch_bounds__(256)
void bucket_deg_kernel(const int* __restrict__ boff, const int* __restrict__ ebuf,
                       int* __restrict__ deg) {
    __shared__ int h[NPB];
    int b = blockIdx.x, t = threadIdx.x;
    for (int i = t; i < NPB; i += 256) h[i] = 0;
    __syncthreads();
    int jb = boff[b], je = boff[b + 1];
    for (int j = jb + t; j < je; j += 256)
        atomicAdd(&h[__builtin_nontemporal_load(&ebuf[j]) >> 17], 1);
    __syncthreads();
    int n0 = b * NPB;
    for (int i = t; i < NPB; i += 256) {
        int n = n0 + i;
        if (n < NN) deg[n] = h[i] + 1;   // +1 self loop
    }
}

// One block per bucket: replay records with LDS cursors; sorted_src writes
// land in this block's exclusive CSR range (L2-local, written back once).
__global__ __launch_bounds__(256)
void bucket_scatter_kernel(const int* __restrict__ boff, const int* __restrict__ ebuf,
                           const int* __restrict__ off, int* __restrict__ sorted_src) {
    __shared__ int lcur[NPB];
    int b = blockIdx.x, t = threadIdx.x;
    int n0 = b * NPB;
    for (int i = t; i < NPB; i += 256) {
        int n = n0 + i;
        lcur[i] = (n < NN) ? off[n] + 1 : 0;   // +1: self loop occupies slot 0
    }
    __syncthreads();
    int jb = boff[b], je = boff[b + 1];
    for (int j = jb + t; j < je; j += 256) {
        int rec = __builtin_nontemporal_load(&ebuf[j]);
        int p = atomicAdd(&lcur[rec >> 17], 1);
        sorted_src[p] = rec & 0x1FFFF;
    }
}

// ---------------- node-offset scan ----------------
__global__ __launch_bounds__(256)
void scan_block_kernel(const int* __restrict__ deg, int* __restrict__ off,
                       int* __restrict__ bsum) {
    __shared__ int s[256];
    int t = threadIdx.x, b = blockIdx.x, i = b * 256 + t;
    int v = (i < NN) ? deg[i] : 0;
    s[t] = v; __syncthreads();
#pragma unroll
    for (int o = 1; o < 256; o <<= 1) {
        int x = (t >= o) ? s[t - o] : 0;
        __syncthreads();
        s[t] += x;
        __syncthreads();
    }
    if (i < NN) off[i] = s[t] - v;
    if (t == 255) bsum[b] = s[255];
}

__global__ __launch_bounds__(256)
void scan_bsum_kernel(const int* __restrict__ bsum, int* __restrict__ bscan, int nb) {
    __shared__ int s[256];
    int t = threadIdx.x;
    int carry = 0;
    int nc = (nb + 255) / 256;
    for (int c = 0; c < nc; c++) {
        int i = c * 256 + t;
        int v = (i < nb) ? bsum[i] : 0;
        s[t] = v; __syncthreads();
#pragma unroll
        for (int o = 1; o < 256; o <<= 1) {
            int x = (t >= o) ? s[t - o] : 0;
            __syncthreads();
            s[t] += x;
            __syncthreads();
        }
        if (i < nb) bscan[i] = carry + s[t] - v;
        carry += s[255];
        __syncthreads();
    }
}

__global__ __launch_bounds__(256)
void place_kernel(int* __restrict__ off, const int* __restrict__ bscan,
                  int* __restrict__ sorted_src) {
    int i = blockIdx.x * 256 + threadIdx.x;
    if (i == 0) off[NN] = NT;
    if (i < NN) {
        int o = off[i] + bscan[i >> 8];
        off[i] = o;
        sorted_src[o] = i;   // self loop first
    }
}

// ---------------- fold weight blocks ----------------
__global__ __launch_bounds__(256)
void fold_B12_kernel(const float* __restrict__ W, const float* __restrict__ lw,
                     const float* __restrict__ as_, const float* __restrict__ ad_,
                     float* __restrict__ B, int F) {
    int t = blockIdx.x * 256 + threadIdx.x;
    if (t >= F * 88) return;
    int f = t / 88, j = t - f * 88;
    float v = 0.f;
    if (j < 40) v = W[f * 40 + j];
    else if (j < 80) v = lw[f * 40 + (j - 40)];
    else if (j < 84) {
        int h = j - 80; float s = 0.f;
        for (int d = 0; d < 10; d++) s += W[f * 40 + h * 10 + d] * as_[h * 10 + d];
        v = s;
    } else {
        int h = j - 84; float s = 0.f;
        for (int d = 0; d < 10; d++) s += W[f * 40 + h * 10 + d] * ad_[h * 10 + d];
        v = s;
    }
    B[t] = v;
}

__global__ __launch_bounds__(256)
void fold_B3_kernel(const float* __restrict__ W3, const float* __restrict__ as3,
                    const float* __restrict__ ad3, float* __restrict__ B) {
    int t = blockIdx.x * 256 + threadIdx.x;
    if (t >= 40 * 12) return;
    int f = t / 12, k = t - f * 12;
    float s = 0.f;
    if (k < 6) {
        int h = k;
        for (int c = 0; c < COUT; c++) s += W3[f * 726 + h * COUT + c] * as3[h * COUT + c];
    } else {
        int h = k - 6;
        for (int c = 0; c < COUT; c++) s += W3[f * 726 + h * COUT + c] * ad3[h * COUT + c];
    }
    B[t] = s;
}

// Fold W3/lw3 into bf16 MFMA B-fragment order.
__global__ __launch_bounds__(256)
void fold_Bf_kernel(const float* __restrict__ W3, const float* __restrict__ lw3,
                    __hip_bfloat16* __restrict__ Bf) {
    int t = blockIdx.x * 256 + threadIdx.x;
    if (t >= 9 * 8 * 64 * 8) return;
    int j = t & 7, lane = (t >> 3) & 63, ct = (t >> 9) & 7, kt = t >> 12;
    int k = kt * 32 + (lane >> 4) * 8 + j;
    int c = ct * 16 + (lane & 15);
    float v = 0.f;
    if (c < COUT) {
        if (k < 240) {
            int h = k / 40, f = k - h * 40;
            v = W3[f * 726 + h * COUT + c];
        } else if (k < 280) {
            int f = k - 240;
            v = lw3[f * COUT + c];
        }
    }
    Bf[t] = __float2bfloat16(v);
}

// ---------------- fused feature GEMM for layers 1/2 ----------------
template <int F>
__global__ __launch_bounds__(256)
void feature12_kernel(const float* __restrict__ A, const float* __restrict__ B,
                      const float* __restrict__ bias, const float* __restrict__ lbias,
                      float* __restrict__ xw, float* __restrict__ agg,
                      float* __restrict__ asrc, float* __restrict__ adst) {
    __shared__ float sB[F * 88];
    const int t = threadIdx.x;
    for (int i = t; i < F * 88; i += 256) sB[i] = B[i];

    const int lane = t & 63;
    const int p = __builtin_amdgcn_readfirstlane(t >> 6);
    const int r = blockIdx.x * 64 + lane;
    const bool valid = r < NN;
    const int rr = valid ? r : NN - 1;

    float a[F];
    if (F % 4 == 0) {
        const float4* A4 = reinterpret_cast<const float4*>(A + (size_t)rr * F);
#pragma unroll
        for (int q = 0; q < F / 4; q++) {
            float4 v = A4[q];
            a[4 * q] = v.x; a[4 * q + 1] = v.y; a[4 * q + 2] = v.z; a[4 * q + 3] = v.w;
        }
    } else {
        const float2* A2 = reinterpret_cast<const float2*>(A + (size_t)rr * F);
#pragma unroll
        for (int q = 0; q < F / 2; q++) {
            float2 v = A2[q];
            a[2 * q] = v.x; a[2 * q + 1] = v.y;
        }
        if (F & 1) a[F - 1] = A[(size_t)rr * F + F - 1];
    }
    __syncthreads();

    for (int g = p; g < 11; g += 4) {
        const int j0 = g * 8;
        float acc[8];
#pragma unroll
        for (int k = 0; k < 8; k++) acc[k] = 0.f;
#pragma unroll
        for (int f = 0; f < F; f++) {
            float av = a[f];
            float4 b0 = *reinterpret_cast<const float4*>(&sB[f * 88 + j0]);
            float4 b1 = *reinterpret_cast<const float4*>(&sB[f * 88 + j0 + 4]);
            acc[0] += av * b0.x; acc[1] += av * b0.y;
            acc[2] += av * b0.z; acc[3] += av * b0.w;
            acc[4] += av * b1.x; acc[5] += av * b1.y;
            acc[6] += av * b1.z; acc[7] += av * b1.w;
        }
        if (!valid) continue;
        if (j0 < 40) {
            *reinterpret_cast<float4*>(xw + (size_t)r * 40 + j0) =
                make_float4(acc[0], acc[1], acc[2], acc[3]);
            *reinterpret_cast<float4*>(xw + (size_t)r * 40 + j0 + 4) =
                make_float4(acc[4], acc[5], acc[6], acc[7]);
        } else if (j0 < 80) {
            int j = j0 - 40;
#pragma unroll
            for (int k = 0; k < 8; k++) acc[k] += bias[j + k] + lbias[j + k];
            *reinterpret_cast<float4*>(agg + (size_t)r * 40 + j) =
                make_float4(acc[0], acc[1], acc[2], acc[3]);
            *reinterpret_cast<float4*>(agg + (size_t)r * 40 + j + 4) =
                make_float4(acc[4], acc[5], acc[6], acc[7]);
        } else {
            *reinterpret_cast<float4*>(asrc + (size_t)r * 8) =
                make_float4(acc[0], acc[1], acc[2], acc[3]);
            *reinterpret_cast<float4*>(adst + (size_t)r * 8) =
                make_float4(acc[4], acc[5], acc[6], acc[7]);
        }
    }
}

// ---------------- layer 3 scores + bf16 h2 copies (zb + packed hp) ----------
__global__ __launch_bounds__(256)
void feature3_kernel(const float* __restrict__ A, const float* __restrict__ B,
                     float* __restrict__ asrc, float* __restrict__ adst,
                     __hip_bfloat16* __restrict__ zb, __hip_bfloat16* __restrict__ hp) {
    int r = blockIdx.x * 256 + threadIdx.x;
    if (r >= NN) return;
    float a[40];
    const float4* A4 = reinterpret_cast<const float4*>(A + (size_t)r * 40);
#pragma unroll
    for (int q = 0; q < 10; q++) {
        float4 v = A4[q];
        a[4 * q] = v.x; a[4 * q + 1] = v.y; a[4 * q + 2] = v.z; a[4 * q + 3] = v.w;
    }
    __hip_bfloat16* zr = zb + (size_t)r * 288 + 240;
    __hip_bfloat16* hr = hp + (size_t)r * 40;
#pragma unroll
    for (int f = 0; f < 40; f++) {
        __hip_bfloat16 v = __float2bfloat16(a[f]);
        zr[f] = v;
        hr[f] = v;
    }
#pragma unroll
    for (int f = 40; f < 48; f++) zr[f] = __float2bfloat16(0.f);

    float acc[12];
#pragma unroll
    for (int k = 0; k < 12; k++) acc[k] = 0.f;
#pragma unroll
    for (int f = 0; f < 40; f++) {
        float av = a[f];
#pragma unroll
        for (int k = 0; k < 12; k++) acc[k] += av * B[f * 12 + k];
    }
    *reinterpret_cast<float4*>(asrc + (size_t)r * 8) = make_float4(acc[0], acc[1], acc[2], acc[3]);
    *reinterpret_cast<float2*>(asrc + (size_t)r * 8 + 4) = make_float2(acc[4], acc[5]);
    *reinterpret_cast<float4*>(adst + (size_t)r * 8) = make_float4(acc[6], acc[7], acc[8], acc[9]);
    *reinterpret_cast<float2*>(adst + (size_t)r * 8 + 4) = make_float2(acc[10], acc[11]);
}

// ---------------- CSR aggregation, H=4, fused weights (LDS), fused ELU ------
// Wave per dst node. Column-major sW[wave][4][72] (conflict-free writes &
// reads). nt loads for the srt stream; nt RMW on agg (each line touched
// once) so the xw gather table stays L2-resident. 8-edge unroll for MLP.
__global__ __launch_bounds__(256)
void agg4_csr_kernel(const int* __restrict__ off, const int* __restrict__ srt,
                     const float* __restrict__ asrc, const float* __restrict__ adst,
                     const float* __restrict__ xw, float* agg) {
    __shared__ float sW[4][4][72];
    __shared__ int   sS[4][64];
    int t = threadIdx.x;
    int wslot = t >> 6;
    int wid = (blockIdx.x * 256 + t) >> 6;
    int d = __builtin_amdgcn_readfirstlane(wid);
    if (d >= NN) return;
    int lane = t & 63;
    bool act = lane < 40;
    int f = act ? lane : 0;
    int hh = f / 10;
    float4 bv = *reinterpret_cast<const float4*>(adst + (size_t)d * 8);
    int jb = off[d], je = off[d + 1];
    float acc = 0.f, ds = 0.f;
    for (int c0 = jb; c0 < je; c0 += 64) {
        int cnt = je - c0; if (cnt > 64) cnt = 64;
        if (lane < cnt) {   // phase A: one lane per edge, conflict-free writes
            int s = __builtin_nontemporal_load(&srt[c0 + lane]);
            sS[wslot][lane] = s * 40;
            float4 a = *reinterpret_cast<const float4*>(asrc + (size_t)s * 8);
            sW[wslot][0][lane] = __expf(lrelu(a.x + bv.x));
            sW[wslot][1][lane] = __expf(lrelu(a.y + bv.y));
            sW[wslot][2][lane] = __expf(lrelu(a.z + bv.z));
            sW[wslot][3][lane] = __expf(lrelu(a.w + bv.w));
        }
        int j = 0;          // phase B: FMA loop (same order as before)
        for (; j + 7 < cnt; j += 8) {
            int4 osA = *reinterpret_cast<const int4*>(&sS[wslot][j]);
            int4 osB = *reinterpret_cast<const int4*>(&sS[wslot][j + 4]);
            float4 wvA = *reinterpret_cast<const float4*>(&sW[wslot][hh][j]);
            float4 wvB = *reinterpret_cast<const float4*>(&sW[wslot][hh][j + 4]);
            float x0 = xw[osA.x + f], x1 = xw[osA.y + f];
            float x2 = xw[osA.z + f], x3 = xw[osA.w + f];
            float x4 = xw[osB.x + f], x5 = xw[osB.y + f];
            float x6 = xw[osB.z + f], x7 = xw[osB.w + f];
            acc += wvA.x * x0; acc += wvA.y * x1; acc += wvA.z * x2; acc += wvA.w * x3;
            ds += (wvA.x + wvA.y) + (wvA.z + wvA.w);
            acc += wvB.x * x4; acc += wvB.y * x5; acc += wvB.z * x6; acc += wvB.w * x7;
            ds += (wvB.x + wvB.y) + (wvB.z + wvB.w);
        }
        for (; j + 3 < cnt; j += 4) {
            int4 os = *reinterpret_cast<const int4*>(&sS[wslot][j]);
            float4 wv = *reinterpret_cast<const float4*>(&sW[wslot][hh][j]);
            float x0 = xw[os.x + f], x1 = xw[os.y + f];
            float x2 = xw[os.z + f], x3 = xw[os.w + f];
            acc += wv.x * x0; acc += wv.y * x1; acc += wv.z * x2; acc += wv.w * x3;
            ds += (wv.x + wv.y) + (wv.z + wv.w);
        }
        for (; j < cnt; ++j) {
            int o = sS[wslot][j];
            float w = sW[wslot][hh][j];
            acc += w * xw[o + f];
            ds += w;
        }
    }
    if (act) {
        float old = __builtin_nontemporal_load(&agg[(size_t)d * 40 + f]);
        float v = old + acc / ds;
        __builtin_nontemporal_store(elu1(v), &agg[(size_t)d * 40 + f]);
    }
}

// ---------------- CSR aggregation, H=6 -> bf16 z, fused weights (LDS) -------
// Column-major sW[wave][6][72]; nt zb stores + nt srt loads keep the 8MB hp
// gather table L2-resident. 8-edge unroll (8 gathers in flight). Denominator
// via per-lane phase-A partials + shfl_xor tree. Per-edge acc order unchanged.
__global__ __launch_bounds__(256)
void z6_csr_kernel(const int* __restrict__ off, const int* __restrict__ srt,
                   const float* __restrict__ asrc, const float* __restrict__ adst,
                   const __hip_bfloat16* __restrict__ hp, __hip_bfloat16* zb) {
    __shared__ float sW[4][6][72];
    __shared__ int   sS[4][64];
    int t = threadIdx.x;
    int wslot = t >> 6;
    int wid = (blockIdx.x * 256 + t) >> 6;
    int d = __builtin_amdgcn_readfirstlane(wid);
    if (d >= NN) return;
    int lane = t & 63;
    bool act = lane < 40;
    int f = act ? lane : 0;
    float4 bv0 = *reinterpret_cast<const float4*>(adst + (size_t)d * 8);
    float2 bv1 = *reinterpret_cast<const float2*>(adst + (size_t)d * 8 + 4);
    int jb = off[d], je = off[d + 1];
    float acc[6], dsp[6];
#pragma unroll
    for (int h = 0; h < 6; h++) { acc[h] = 0.f; dsp[h] = 0.f; }
    for (int c0 = jb; c0 < je; c0 += 64) {
        int cnt = je - c0; if (cnt > 64) cnt = 64;
        if (lane < cnt) {   // phase A: one lane per edge; private ds partials
            int s = __builtin_nontemporal_load(&srt[c0 + lane]);
            sS[wslot][lane] = s * 40;
            float4 a0 = *reinterpret_cast<const float4*>(asrc + (size_t)s * 8);
            float2 a1 = *reinterpret_cast<const float2*>(asrc + (size_t)s * 8 + 4);
            float w0 = __expf(lrelu(a0.x + bv0.x));
            float w1 = __expf(lrelu(a0.y + bv0.y));
            float w2 = __expf(lrelu(a0.z + bv0.z));
            float w3 = __expf(lrelu(a0.w + bv0.w));
            float w4 = __expf(lrelu(a1.x + bv1.x));
            float w5 = __expf(lrelu(a1.y + bv1.y));
            sW[wslot][0][lane] = w0; sW[wslot][1][lane] = w1;
            sW[wslot][2][lane] = w2; sW[wslot][3][lane] = w3;
            sW[wslot][4][lane] = w4; sW[wslot][5][lane] = w5;
            dsp[0] += w0; dsp[1] += w1; dsp[2] += w2;
            dsp[3] += w3; dsp[4] += w4; dsp[5] += w5;
        }
        int j = 0;          // phase B: acc order = edge order (unchanged)
        for (; j + 7 < cnt; j += 8) {
            int4 osA = *reinterpret_cast<const int4*>(&sS[wslot][j]);
            int4 osB = *reinterpret_cast<const int4*>(&sS[wslot][j + 4]);
            float hv0 = __bfloat162float(hp[osA.x + f]);
            float hv1 = __bfloat162float(hp[osA.y + f]);
            float hv2 = __bfloat162float(hp[osA.z + f]);
            float hv3 = __bfloat162float(hp[osA.w + f]);
            float hv4 = __bfloat162float(hp[osB.x + f]);
            float hv5 = __bfloat162float(hp[osB.y + f]);
            float hv6 = __bfloat162float(hp[osB.z + f]);
            float hv7 = __bfloat162float(hp[osB.w + f]);
            float4 wA0 = *reinterpret_cast<const float4*>(&sW[wslot][0][j]);
            float4 wA1 = *reinterpret_cast<const float4*>(&sW[wslot][1][j]);
            float4 wA2 = *reinterpret_cast<const float4*>(&sW[wslot][2][j]);
            float4 wA3 = *reinterpret_cast<const float4*>(&sW[wslot][3][j]);
            float4 wA4 = *reinterpret_cast<const float4*>(&sW[wslot][4][j]);
            float4 wA5 = *reinterpret_cast<const float4*>(&sW[wslot][5][j]);
            float4 wB0 = *reinterpret_cast<const float4*>(&sW[wslot][0][j + 4]);
            float4 wB1 = *reinterpret_cast<const float4*>(&sW[wslot][1][j + 4]);
            float4 wB2 = *reinterpret_cast<const float4*>(&sW[wslot][2][j + 4]);
            float4 wB3 = *reinterpret_cast<const float4*>(&sW[wslot][3][j + 4]);
            float4 wB4 = *reinterpret_cast<const float4*>(&sW[wslot][4][j + 4]);
            float4 wB5 = *reinterpret_cast<const float4*>(&sW[wslot][5][j + 4]);
            acc[0] += wA0.x * hv0; acc[1] += wA1.x * hv0; acc[2] += wA2.x * hv0;
            acc[3] += wA3.x * hv0; acc[4] += wA4.x * hv0; acc[5] += wA5.x * hv0;
            acc[0] += wA0.y * hv1; acc[1] += wA1.y * hv1; acc[2] += wA2.y * hv1;
            acc[3] += wA3.y * hv1; acc[4] += wA4.y * hv1; acc[5] += wA5.y * hv1;
            acc[0] += wA0.z * hv2; acc[1] += wA1.z * hv2; acc[2] += wA2.z * hv2;
            acc[3] += wA3.z * hv2; acc[4] += wA4.z * hv2; acc[5] += wA5.z * hv2;
            acc[0] += wA0.w * hv3; acc[1] += wA1.w * hv3; acc[2] += wA2.w * hv3;
            acc[3] += wA3.w * hv3; acc[4] += wA4.w * hv3; acc[5] += wA5.w * hv3;
            acc[0] += wB0.x * hv4; acc[1] += wB1.x * hv4; acc[2] += wB2.x * hv4;
            acc[3] += wB3.x * hv4; acc[4] += wB4.x * hv4; acc[5] += wB5.x * hv4;
            acc[0] += wB0.y * hv5; acc[1] += wB1.y * hv5; acc[2] += wB2.y * hv5;
            acc[3] += wB3.y * hv5; acc[4] += wB4.y * hv5; acc[5] += wB5.y * hv5;
            acc[0] += wB0.z * hv6; acc[1] += wB1.z * hv6; acc[2] += wB2.z * hv6;
            acc[3] += wB3.z * hv6; acc[4] += wB4.z * hv6; acc[5] += wB5.z * hv6;
            acc[0] += wB0.w * hv7; acc[1] += wB1.w * hv7; acc[2] += wB2.w * hv7;
            acc[3] += wB3.w * hv7; acc[4] += wB4.w * hv7; acc[5] += wB5.w * hv7;
        }
        for (; j + 3 < cnt; j += 4) {
            int4 os = *reinterpret_cast<const int4*>(&sS[wslot][j]);
            float hv0 = __bfloat162float(hp[os.x + f]);
            float hv1 = __bfloat162float(hp[os.y + f]);
            float hv2 = __bfloat162float(hp[os.z + f]);
            float hv3 = __bfloat162float(hp[os.w + f]);
            float4 wv0 = *reinterpret_cast<const float4*>(&sW[wslot][0][j]);
            float4 wv1 = *reinterpret_cast<const float4*>(&sW[wslot][1][j]);
            float4 wv2 = *reinterpret_cast<const float4*>(&sW[wslot][2][j]);
            float4 wv3 = *reinterpret_cast<const float4*>(&sW[wslot][3][j]);
            float4 wv4 = *reinterpret_cast<const float4*>(&sW[wslot][4][j]);
            float4 wv5 = *reinterpret_cast<const float4*>(&sW[wslot][5][j]);
            acc[0] += wv0.x * hv0; acc[1] += wv1.x * hv0; acc[2] += wv2.x * hv0;
            acc[3] += wv3.x * hv0; acc[4] += wv4.x * hv0; acc[5] += wv5.x * hv0;
            acc[0] += wv0.y * hv1; acc[1] += wv1.y * hv1; acc[2] += wv2.y * hv1;
            acc[3] += wv3.y * hv1; acc[4] += wv4.y * hv1; acc[5] += wv5.y * hv1;
            acc[0] += wv0.z * hv2; acc[1] += wv1.z * hv2; acc[2] += wv2.z * hv2;
            acc[3] += wv3.z * hv2; acc[4] += wv4.z * hv2; acc[5] += wv5.z * hv2;
            acc[0] += wv0.w * hv3; acc[1] += wv1.w * hv3; acc[2] += wv2.w * hv3;
            acc[3] += wv3.w * hv3; acc[4] += wv4.w * hv3; acc[5] += wv5.w * hv3;
        }
        for (; j < cnt; ++j) {
            int o = sS[wslot][j];
            float hv = __bfloat162float(hp[o + f]);
            acc[0] += sW[wslot][0][j] * hv; acc[1] += sW[wslot][1][j] * hv;
            acc[2] += sW[wslot][2][j] * hv; acc[3] += sW[wslot][3][j] * hv;
            acc[4] += sW[wslot][4][j] * hv; acc[5] += sW[wslot][5][j] * hv;
        }
    }
    // reduce per-lane denominator partials across the wave (tree order)
#pragma unroll
    for (int h = 0; h < 6; h++) {
        float v = dsp[h];
#pragma unroll
        for (int o = 1; o < 64; o <<= 1) v += __shfl_xor(v, o, 64);
        dsp[h] = v;
    }
    if (act) {
#pragma unroll
        for (int h = 0; h < 6; h++) {
            __hip_bfloat16 v = __float2bfloat16(acc[h] / dsp[h] * (1.0f / 6.0f));
            __builtin_nontemporal_store(
                *reinterpret_cast<unsigned short*>(&v),
                reinterpret_cast<unsigned short*>(&zb[(size_t)d * 288 + h * 40 + f]));
        }
    }
}

// ---------------- MFMA GEMM: out[100000x121] = A[100000x288]@B[288x128] + bias
__global__ __launch_bounds__(256)
void zgemm_mfma_kernel(const __hip_bfloat16* __restrict__ Ab,
                       const __hip_bfloat16* __restrict__ Bf,
                       const float* __restrict__ b3, const float* __restrict__ lb3,
                       float* __restrict__ out) {
    const int t = threadIdx.x;
    const int lane = t & 63, w = t >> 6;
    const int wr = w & 1, wc = w >> 1;
    const int n0 = blockIdx.x * 128;
    const short* As = (const short*)Ab;
    const short* Bs = (const short*)Bf;

    f32x4 acc[4][4];
#pragma unroll
    for (int i = 0; i < 4; i++)
#pragma unroll
        for (int j = 0; j < 4; j++) acc[i][j] = (f32x4){0.f, 0.f, 0.f, 0.f};

    const int arow = n0 + wr * 64 + (lane & 15);
    const int koff = (lane >> 4) * 8;

    for (int kk = 0; kk < 9; kk++) {
        bf16x8 af[4], bfr[4];
#pragma unroll
        for (int i = 0; i < 4; i++) {
            int r = arow + i * 16; if (r > NN - 1) r = NN - 1;
            af[i] = *(const bf16x8*)(As + (size_t)r * 288 + kk * 32 + koff);
        }
#pragma unroll
        for (int j = 0; j < 4; j++) {
            int ct = wc * 4 + j;
            bfr[j] = *(const bf16x8*)(Bs + (((size_t)kk * 8 + ct) * 64 + lane) * 8);
        }
#pragma unroll
        for (int i = 0; i < 4; i++)
#pragma unroll
            for (int j = 0; j < 4; j++)
                acc[i][j] = __builtin_amdgcn_mfma_f32_16x16x32_bf16(af[i], bfr[j], acc[i][j], 0, 0, 0);
    }

    const int c_base = wc * 64 + (lane & 15);
    const int r_quad = (lane >> 4) * 4;
#pragma unroll
    for (int j = 0; j < 4; j++) {
        int c = c_base + j * 16;
        if (c >= COUT) continue;
        float bias = b3[c] + lb3[c];
#pragma unroll
        for (int i = 0; i < 4; i++) {
            int nb = n0 + wr * 64 + i * 16 + r_quad;
#pragma unroll
            for (int q = 0; q < 4; q++) {
                int n = nb + q;
                if (n < NN) out[(size_t)n * COUT + c] = acc[i][j][q] + bias;
            }
        }
    }
}

extern "C" void kernel_launch(void* const* d_in, const int* in_sizes, int n_in,
                              void* d_out, int out_size, void* d_ws, size_t ws_size,
                              hipStream_t stream) {
    const float* x   = (const float*)d_in[0];
    const int*   ei  = (const int*)d_in[1];
    const float* W1  = (const float*)d_in[2];
    const float* as1 = (const float*)d_in[3];
    const float* ad1 = (const float*)d_in[4];
    const float* b1  = (const float*)d_in[5];
    const float* lw1 = (const float*)d_in[6];
    const float* lb1 = (const float*)d_in[7];
    const float* W2  = (const float*)d_in[8];
    const float* as2 = (const float*)d_in[9];
    const float* ad2 = (const float*)d_in[10];
    const float* b2  = (const float*)d_in[11];
    const float* lw2 = (const float*)d_in[12];
    const float* lb2 = (const float*)d_in[13];
    const float* W3  = (const float*)d_in[14];
    const float* as3 = (const float*)d_in[15];
    const float* ad3 = (const float*)d_in[16];
    const float* b3  = (const float*)d_in[17];
    const float* lw3 = (const float*)d_in[18];
    const float* lb3 = (const float*)d_in[19];
    float* out = (float*)d_out;
    float* ws  = (float*)d_ws;

    const int* esrc = ei;
    const int* edst = ei + NE;

    // ---- workspace layout (floats unless noted) ----
    float* xw   = ws;
    float* agg  = ws + 4000000;
    float* asrc = ws + 8000000;
    float* adst = ws + 8800000;
    float* Bc   = ws + 9600000;
    __hip_bfloat16* Bf = (__hip_bfloat16*)(ws + 9608000);
    __hip_bfloat16* zb = (__hip_bfloat16*)(ws + 9628000);
    __hip_bfloat16* hp = (__hip_bfloat16*)ws; // aliases xw (layer 3 only)
    int* ib     = (int*)(ws + 24028000);
    int* deg    = ib;                 // 100,352
    int* off    = ib + 100352;        // 100,001 (+pad)
    int* bcnt   = ib + 200704;        // 128
    int* boff   = ib + 200832;        // 129
    int* bcur   = ib + 200992;        // 128
    int* bsum   = ib + 300704;        // 512
    int* bscan  = ib + 301216;        // 512
    int* sorted = ib + 301728;        // 1,700,000 -> ends 2,001,728
    int* ebuf   = ib + 2001728;       // 1,600,000 -> ends 3,601,728

    const int nodeBlocks = (NN + 255) / 256;       // 391
    const int binBlocks  = (NE + EPB - 1) / EPB;   // 196
    const int waveBlocks = NN / 4;                 // 25000
    const int featBlocks = (NN + 63) / 64;         // 1563 (64 rows/block)

    // ---- bucketed CSR build ----
    zero_bcnt_kernel<<<1, 256, 0, stream>>>(bcnt);
    bin_count_kernel<<<binBlocks, 256, 0, stream>>>(edst, bcnt);
    bin_scan_kernel<<<1, 256, 0, stream>>>(bcnt, boff, bcur);
    bin_place_kernel<<<binBlocks, 256, 0, stream>>>(esrc, edst, bcur, ebuf);
    bucket_deg_kernel<<<NB, 256, 0, stream>>>(boff, ebuf, deg);
    scan_block_kernel<<<nodeBlocks, 256, 0, stream>>>(deg, off, bsum);
    scan_bsum_kernel<<<1, 256, 0, stream>>>(bsum, bscan, nodeBlocks);
    place_kernel<<<nodeBlocks, 256, 0, stream>>>(off, bscan, sorted);
    bucket_scatter_kernel<<<NB, 256, 0, stream>>>(boff, ebuf, off, sorted);

    // ---- layer 1 ----
    fold_B12_kernel<<<(FIN * 88 + 255) / 256, 256, 0, stream>>>(W1, lw1, as1, ad1, Bc, FIN);
    feature12_kernel<FIN><<<featBlocks, 256, 0, stream>>>(x, Bc, b1, lb1, xw, agg, asrc, adst);
    agg4_csr_kernel<<<waveBlocks, 256, 0, stream>>>(off, sorted, asrc, adst, xw, agg);

    // ---- layer 2 ----
    fold_B12_kernel<<<(HID * 88 + 255) / 256, 256, 0, stream>>>(W2, lw2, as2, ad2, Bc, HID);
    feature12_kernel<HID><<<featBlocks, 256, 0, stream>>>(agg, Bc, b2, lb2, xw, agg, asrc, adst);
    agg4_csr_kernel<<<waveBlocks, 256, 0, stream>>>(off, sorted, asrc, adst, xw, agg);

    // ---- layer 3 ----
    fold_B3_kernel<<<(40 * 12 + 255) / 256, 256, 0, stream>>>(W3, as3, ad3, Bc);
    fold_Bf_kernel<<<(9 * 8 * 64 * 8 + 255) / 256, 256, 0, stream>>>(W3, lw3, Bf);
    feature3_kernel<<<nodeBlocks, 256, 0, stream>>>(agg, Bc, asrc, adst, zb, hp);
    z6_csr_kernel<<<waveBlocks, 256, 0, stream>>>(off, sorted, asrc, adst, hp, zb);
    zgemm_mfma_kernel<<<(NN + 127) / 128, 256, 0, stream>>>(zb, Bf, b3, lb3, out);
}

// Round 9
// 539.982 us; speedup vs baseline: 1.1355x; 1.1355x over previous
//
#include <hip/hip_runtime.h>
#include <hip/hip_bf16.h>
#include <math.h>

// GAT x3 on N=100000 nodes, E=1600000 edges (+ self loops).
// Round 14: revert z6/agg4 inner loops to the round-10 structure (83us z6,
// best measured; r11-r13 micro-opts all regressed: r11 LDS write conflicts,
// r12 slower despite fewer LDS ops, r13 VGPR/occupancy blowup + nt-store
// write amplification). New change is LAYOUT-ONLY: split gather tables so
// the hot row is one aligned 64B line:
//   hp (80B rows, 2-3 lines/gather) -> hpA[node][0:32] 64B aligned rows
//     (1 line/edge) + hpB[node][32:40] 16B rows (1.6MB, L2-resident)
//   xw (160B rows, avg 2.75 lines) -> xwA[node][0:32] 128B aligned rows
//     + xwB[node][32:40] 32B rows (3.2MB)
// Same values, same FMA order -> bit-identical numerics.
// (R10: fused weights in LDS; R9: feature12 LDS-B; R8: bucketed CSR.)

#define NN 100000
#define NE 1600000
#define NT (NE + NN)
#define FIN 50
#define HID 40
#define COUT 121

#define NB 128           // buckets
#define NPB 782          // nodes per bucket (128*782 = 100096 >= NN)
#define EPB 8192         // edges per bin block

typedef __attribute__((ext_vector_type(8))) short bf16x8;
typedef __attribute__((ext_vector_type(4))) float f32x4;

__device__ __forceinline__ float lrelu(float x) { return fmaxf(x, 0.2f * x); }
__device__ __forceinline__ float elu1(float x)  { return x > 0.f ? x : __expf(x) - 1.f; }

// ---------------- bucketed CSR build ----------------
__global__ __launch_bounds__(256)
void zero_bcnt_kernel(int* __restrict__ bcnt) {
    int t = threadIdx.x;
    if (t < NB) bcnt[t] = 0;
}

__global__ __launch_bounds__(256)
void bin_count_kernel(const int* __restrict__ edst, int* __restrict__ bcnt) {
    __shared__ int h[NB];
    int t = threadIdx.x;
    if (t < NB) h[t] = 0;
    __syncthreads();
    int e0 = blockIdx.x * EPB;
    for (int q = 0; q < EPB; q += 256) {
        int e = e0 + q + t;
        if (e < NE) atomicAdd(&h[edst[e] / NPB], 1);
    }
    __syncthreads();
    if (t < NB && h[t]) atomicAdd(&bcnt[t], h[t]);
}

__global__ __launch_bounds__(256)
void bin_scan_kernel(const int* __restrict__ bcnt, int* __restrict__ boff,
                     int* __restrict__ bcur) {
    __shared__ int s[NB];
    int t = threadIdx.x;
    if (t < NB) s[t] = bcnt[t];
    __syncthreads();
    if (t == 0) {
        int run = 0;
        for (int i = 0; i < NB; i++) { int c = s[i]; s[i] = run; run += c; }
        boff[NB] = run;   // == NE
    }
    __syncthreads();
    if (t < NB) { boff[t] = s[t]; bcur[t] = s[t]; }
}

// Each block claims a contiguous chunk per bucket, then writes packed records
// src | (dst_in_bucket << 17) into its exclusive chunk (dense, short window).
__global__ __launch_bounds__(256)
void bin_place_kernel(const int* __restrict__ esrc, const int* __restrict__ edst,
                      int* __restrict__ bcur, int* __restrict__ ebuf) {
    __shared__ int h[NB], base[NB], lcur[NB];
    int t = threadIdx.x;
    if (t < NB) h[t] = 0;
    __syncthreads();
    int e0 = blockIdx.x * EPB;
    for (int q = 0; q < EPB; q += 256) {
        int e = e0 + q + t;
        if (e < NE) atomicAdd(&h[edst[e] / NPB], 1);
    }
    __syncthreads();
    if (t < NB) {
        int c = h[t];
        base[t] = c ? atomicAdd(&bcur[t], c) : 0;
        lcur[t] = 0;
    }
    __syncthreads();
    for (int q = 0; q < EPB; q += 256) {
        int e = e0 + q + t;
        if (e < NE) {
            int d = edst[e], s = esrc[e];
            int b = d / NPB;
            int r = atomicAdd(&lcur[b], 1);
            ebuf[base[b] + r] = s | ((d - b * NPB) << 17);
        }
    }
}

// One block per bucket: per-node degree via LDS histogram.
__global__ __launch_bounds__(256)
void bucket_deg_kernel(const int* __restrict__ boff, const int* __restrict__ ebuf,
                       int* __restrict__ deg) {
    __shared__ int h[NPB];
    int b = blockIdx.x, t = threadIdx.x;
    for (int i = t; i < NPB; i += 256) h[i] = 0;
    __syncthreads();
    int jb = boff[b], je = boff[b + 1];
    for (int j = jb + t; j < je; j += 256) atomicAdd(&h[ebuf[j] >> 17], 1);
    __syncthreads();
    int n0 = b * NPB;
    for (int i = t; i < NPB; i += 256) {
        int n = n0 + i;
        if (n < NN) deg[n] = h[i] + 1;   // +1 self loop
    }
}

// One block per bucket: replay records with LDS cursors; sorted_src writes
// land in this block's exclusive CSR range (L2-local, written back once).
__global__ __launch_bounds__(256)
void bucket_scatter_kernel(const int* __restrict__ boff, const int* __restrict__ ebuf,
                           const int* __restrict__ off, int* __restrict__ sorted_src) {
    __shared__ int lcur[NPB];
    int b = blockIdx.x, t = threadIdx.x;
    int n0 = b * NPB;
    for (int i = t; i < NPB; i += 256) {
        int n = n0 + i;
        lcur[i] = (n < NN) ? off[n] + 1 : 0;   // +1: self loop occupies slot 0
    }
    __syncthreads();
    int jb = boff[b], je = boff[b + 1];
    for (int j = jb + t; j < je; j += 256) {
        int rec = ebuf[j];
        int p = atomicAdd(&lcur[rec >> 17], 1);
        sorted_src[p] = rec & 0x1FFFF;
    }
}

// ---------------- node-offset scan ----------------
__global__ __launch_bounds__(256)
void scan_block_kernel(const int* __restrict__ deg, int* __restrict__ off,
                       int* __restrict__ bsum) {
    __shared__ int s[256];
    int t = threadIdx.x, b = blockIdx.x, i = b * 256 + t;
    int v = (i < NN) ? deg[i] : 0;
    s[t] = v; __syncthreads();
#pragma unroll
    for (int o = 1; o < 256; o <<= 1) {
        int x = (t >= o) ? s[t - o] : 0;
        __syncthreads();
        s[t] += x;
        __syncthreads();
    }
    if (i < NN) off[i] = s[t] - v;
    if (t == 255) bsum[b] = s[255];
}

__global__ __launch_bounds__(256)
void scan_bsum_kernel(const int* __restrict__ bsum, int* __restrict__ bscan, int nb) {
    __shared__ int s[256];
    int t = threadIdx.x;
    int carry = 0;
    int nc = (nb + 255) / 256;
    for (int c = 0; c < nc; c++) {
        int i = c * 256 + t;
        int v = (i < nb) ? bsum[i] : 0;
        s[t] = v; __syncthreads();
#pragma unroll
        for (int o = 1; o < 256; o <<= 1) {
            int x = (t >= o) ? s[t - o] : 0;
            __syncthreads();
            s[t] += x;
            __syncthreads();
        }
        if (i < nb) bscan[i] = carry + s[t] - v;
        carry += s[255];
        __syncthreads();
    }
}

__global__ __launch_bounds__(256)
void place_kernel(int* __restrict__ off, const int* __restrict__ bscan,
                  int* __restrict__ sorted_src) {
    int i = blockIdx.x * 256 + threadIdx.x;
    if (i == 0) off[NN] = NT;
    if (i < NN) {
        int o = off[i] + bscan[i >> 8];
        off[i] = o;
        sorted_src[o] = i;   // self loop first
    }
}

// ---------------- fold weight blocks ----------------
__global__ __launch_bounds__(256)
void fold_B12_kernel(const float* __restrict__ W, const float* __restrict__ lw,
                     const float* __restrict__ as_, const float* __restrict__ ad_,
                     float* __restrict__ B, int F) {
    int t = blockIdx.x * 256 + threadIdx.x;
    if (t >= F * 88) return;
    int f = t / 88, j = t - f * 88;
    float v = 0.f;
    if (j < 40) v = W[f * 40 + j];
    else if (j < 80) v = lw[f * 40 + (j - 40)];
    else if (j < 84) {
        int h = j - 80; float s = 0.f;
        for (int d = 0; d < 10; d++) s += W[f * 40 + h * 10 + d] * as_[h * 10 + d];
        v = s;
    } else {
        int h = j - 84; float s = 0.f;
        for (int d = 0; d < 10; d++) s += W[f * 40 + h * 10 + d] * ad_[h * 10 + d];
        v = s;
    }
    B[t] = v;
}

__global__ __launch_bounds__(256)
void fold_B3_kernel(const float* __restrict__ W3, const float* __restrict__ as3,
                    const float* __restrict__ ad3, float* __restrict__ B) {
    int t = blockIdx.x * 256 + threadIdx.x;
    if (t >= 40 * 12) return;
    int f = t / 12, k = t - f * 12;
    float s = 0.f;
    if (k < 6) {
        int h = k;
        for (int c = 0; c < COUT; c++) s += W3[f * 726 + h * COUT + c] * as3[h * COUT + c];
    } else {
        int h = k - 6;
        for (int c = 0; c < COUT; c++) s += W3[f * 726 + h * COUT + c] * ad3[h * COUT + c];
    }
    B[t] = s;
}

// Fold W3/lw3 into bf16 MFMA B-fragment order.
__global__ __launch_bounds__(256)
void fold_Bf_kernel(const float* __restrict__ W3, const float* __restrict__ lw3,
                    __hip_bfloat16* __restrict__ Bf) {
    int t = blockIdx.x * 256 + threadIdx.x;
    if (t >= 9 * 8 * 64 * 8) return;
    int j = t & 7, lane = (t >> 3) & 63, ct = (t >> 9) & 7, kt = t >> 12;
    int k = kt * 32 + (lane >> 4) * 8 + j;
    int c = ct * 16 + (lane & 15);
    float v = 0.f;
    if (c < COUT) {
        if (k < 240) {
            int h = k / 40, f = k - h * 40;
            v = W3[f * 726 + h * COUT + c];
        } else if (k < 280) {
            int f = k - 240;
            v = lw3[f * COUT + c];
        }
    }
    Bf[t] = __float2bfloat16(v);
}

// ---------------- fused feature GEMM for layers 1/2 ----------------
// Split xw stores: f<32 -> xwA (128B aligned rows), f in [32,40) -> xwB
// (32B rows). j0 in {0,8,16,24} -> xwA; j0 == 32 -> xwB. Same values.
template <int F>
__global__ __launch_bounds__(256)
void feature12_kernel(const float* __restrict__ A, const float* __restrict__ B,
                      const float* __restrict__ bias, const float* __restrict__ lbias,
                      float* __restrict__ xwA, float* __restrict__ xwB,
                      float* __restrict__ agg,
                      float* __restrict__ asrc, float* __restrict__ adst) {
    __shared__ float sB[F * 88];
    const int t = threadIdx.x;
    for (int i = t; i < F * 88; i += 256) sB[i] = B[i];

    const int lane = t & 63;
    const int p = __builtin_amdgcn_readfirstlane(t >> 6);
    const int r = blockIdx.x * 64 + lane;
    const bool valid = r < NN;
    const int rr = valid ? r : NN - 1;

    float a[F];
    if (F % 4 == 0) {
        const float4* A4 = reinterpret_cast<const float4*>(A + (size_t)rr * F);
#pragma unroll
        for (int q = 0; q < F / 4; q++) {
            float4 v = A4[q];
            a[4 * q] = v.x; a[4 * q + 1] = v.y; a[4 * q + 2] = v.z; a[4 * q + 3] = v.w;
        }
    } else {
        const float2* A2 = reinterpret_cast<const float2*>(A + (size_t)rr * F);
#pragma unroll
        for (int q = 0; q < F / 2; q++) {
            float2 v = A2[q];
            a[2 * q] = v.x; a[2 * q + 1] = v.y;
        }
        if (F & 1) a[F - 1] = A[(size_t)rr * F + F - 1];
    }
    __syncthreads();

    for (int g = p; g < 11; g += 4) {
        const int j0 = g * 8;
        float acc[8];
#pragma unroll
        for (int k = 0; k < 8; k++) acc[k] = 0.f;
#pragma unroll
        for (int f = 0; f < F; f++) {
            float av = a[f];
            float4 b0 = *reinterpret_cast<const float4*>(&sB[f * 88 + j0]);
            float4 b1 = *reinterpret_cast<const float4*>(&sB[f * 88 + j0 + 4]);
            acc[0] += av * b0.x; acc[1] += av * b0.y;
            acc[2] += av * b0.z; acc[3] += av * b0.w;
            acc[4] += av * b1.x; acc[5] += av * b1.y;
            acc[6] += av * b1.z; acc[7] += av * b1.w;
        }
        if (!valid) continue;
        if (j0 < 32) {
            *reinterpret_cast<float4*>(xwA + (size_t)r * 32 + j0) =
                make_float4(acc[0], acc[1], acc[2], acc[3]);
            *reinterpret_cast<float4*>(xwA + (size_t)r * 32 + j0 + 4) =
                make_float4(acc[4], acc[5], acc[6], acc[7]);
        } else if (j0 < 40) {   // j0 == 32
            *reinterpret_cast<float4*>(xwB + (size_t)r * 8) =
                make_float4(acc[0], acc[1], acc[2], acc[3]);
            *reinterpret_cast<float4*>(xwB + (size_t)r * 8 + 4) =
                make_float4(acc[4], acc[5], acc[6], acc[7]);
        } else if (j0 < 80) {
            int j = j0 - 40;
#pragma unroll
            for (int k = 0; k < 8; k++) acc[k] += bias[j + k] + lbias[j + k];
            *reinterpret_cast<float4*>(agg + (size_t)r * 40 + j) =
                make_float4(acc[0], acc[1], acc[2], acc[3]);
            *reinterpret_cast<float4*>(agg + (size_t)r * 40 + j + 4) =
                make_float4(acc[4], acc[5], acc[6], acc[7]);
        } else {
            *reinterpret_cast<float4*>(asrc + (size_t)r * 8) =
                make_float4(acc[0], acc[1], acc[2], acc[3]);
            *reinterpret_cast<float4*>(adst + (size_t)r * 8) =
                make_float4(acc[4], acc[5], acc[6], acc[7]);
        }
    }
}

// ---------------- layer 3 scores + bf16 h2 copies (zb + split hpA/hpB) ------
__global__ __launch_bounds__(256)
void feature3_kernel(const float* __restrict__ A, const float* __restrict__ B,
                     float* __restrict__ asrc, float* __restrict__ adst,
                     __hip_bfloat16* __restrict__ zb,
                     __hip_bfloat16* __restrict__ hpA, __hip_bfloat16* __restrict__ hpB) {
    int r = blockIdx.x * 256 + threadIdx.x;
    if (r >= NN) return;
    float a[40];
    const float4* A4 = reinterpret_cast<const float4*>(A + (size_t)r * 40);
#pragma unroll
    for (int q = 0; q < 10; q++) {
        float4 v = A4[q];
        a[4 * q] = v.x; a[4 * q + 1] = v.y; a[4 * q + 2] = v.z; a[4 * q + 3] = v.w;
    }
    __hip_bfloat16* zr = zb + (size_t)r * 288 + 240;
    __hip_bfloat16* ha = hpA + (size_t)r * 32;
    __hip_bfloat16* hb = hpB + (size_t)r * 8;
#pragma unroll
    for (int f = 0; f < 40; f++) {
        __hip_bfloat16 v = __float2bfloat16(a[f]);
        zr[f] = v;
        if (f < 32) ha[f] = v; else hb[f - 32] = v;
    }
#pragma unroll
    for (int f = 40; f < 48; f++) zr[f] = __float2bfloat16(0.f);

    float acc[12];
#pragma unroll
    for (int k = 0; k < 12; k++) acc[k] = 0.f;
#pragma unroll
    for (int f = 0; f < 40; f++) {
        float av = a[f];
#pragma unroll
        for (int k = 0; k < 12; k++) acc[k] += av * B[f * 12 + k];
    }
    *reinterpret_cast<float4*>(asrc + (size_t)r * 8) = make_float4(acc[0], acc[1], acc[2], acc[3]);
    *reinterpret_cast<float2*>(asrc + (size_t)r * 8 + 4) = make_float2(acc[4], acc[5]);
    *reinterpret_cast<float4*>(adst + (size_t)r * 8) = make_float4(acc[6], acc[7], acc[8], acc[9]);
    *reinterpret_cast<float2*>(adst + (size_t)r * 8 + 4) = make_float2(acc[10], acc[11]);
}

// ---------------- CSR aggregation, H=4, fused weights (LDS), fused ELU ------
// Round-10 structure. Gather table split: lane f<32 reads xwA[s*32+f]
// (128B-aligned rows), f>=32 reads xwB[s*8+f-32] (3.2MB, L2-resident).
__global__ __launch_bounds__(256)
void agg4_csr_kernel(const int* __restrict__ off, const int* __restrict__ srt,
                     const float* __restrict__ asrc, const float* __restrict__ adst,
                     const float* __restrict__ xwA, const float* __restrict__ xwB,
                     float* agg) {
    __shared__ float sW[4][64 * 4];
    __shared__ int   sS[4][64];
    int t = threadIdx.x;
    int wslot = t >> 6;
    int wid = (blockIdx.x * 256 + t) >> 6;
    int d = __builtin_amdgcn_readfirstlane(wid);
    if (d >= NN) return;
    int lane = t & 63;
    bool act = lane < 40;
    int f = act ? lane : 0;
    int hh = f / 10;
    const float* xt = (f < 32) ? xwA : xwB;
    const int sh = (f < 32) ? 5 : 3;
    const int fo = (f < 32) ? f : (f - 32);
    float4 bv = *reinterpret_cast<const float4*>(adst + (size_t)d * 8);
    int jb = off[d], je = off[d + 1];
    float acc = 0.f, ds = 0.f;
    for (int c0 = jb; c0 < je; c0 += 64) {
        int cnt = je - c0; if (cnt > 64) cnt = 64;
        if (lane < cnt) {   // phase A: one lane per edge
            int s = srt[c0 + lane];
            sS[wslot][lane] = s;
            float4 a = *reinterpret_cast<const float4*>(asrc + (size_t)s * 8);
            float4 w;
            w.x = __expf(lrelu(a.x + bv.x));
            w.y = __expf(lrelu(a.y + bv.y));
            w.z = __expf(lrelu(a.z + bv.z));
            w.w = __expf(lrelu(a.w + bv.w));
            *reinterpret_cast<float4*>(&sW[wslot][lane * 4]) = w;
        }
        int j = 0;          // phase B: FMA loop (round-10 order)
        for (; j + 3 < cnt; j += 4) {
            int s0 = sS[wslot][j], s1 = sS[wslot][j + 1];
            int s2 = sS[wslot][j + 2], s3 = sS[wslot][j + 3];
            float w0 = sW[wslot][(j + 0) * 4 + hh];
            float w1 = sW[wslot][(j + 1) * 4 + hh];
            float w2 = sW[wslot][(j + 2) * 4 + hh];
            float w3 = sW[wslot][(j + 3) * 4 + hh];
            float x0 = xt[((size_t)s0 << sh) + fo], x1 = xt[((size_t)s1 << sh) + fo];
            float x2 = xt[((size_t)s2 << sh) + fo], x3 = xt[((size_t)s3 << sh) + fo];
            acc += w0 * x0; acc += w1 * x1; acc += w2 * x2; acc += w3 * x3;
            ds += (w0 + w1) + (w2 + w3);
        }
        for (; j < cnt; ++j) {
            int s = sS[wslot][j];
            float w = sW[wslot][j * 4 + hh];
            acc += w * xt[((size_t)s << sh) + fo];
            ds += w;
        }
    }
    if (act) {
        float v = agg[(size_t)d * 40 + f] + acc / ds;
        agg[(size_t)d * 40 + f] = elu1(v);   // ELU fused (layers 1/2 only)
    }
}

// ---------------- CSR aggregation, H=6 -> bf16 z, fused weights (LDS) -------
// Round-10 structure. Gather table split: lane f<32 reads hpA[s*32+f]
// (64B-aligned rows = ONE line/edge), f>=32 reads hpB[s*8+f-32] (1.6MB).
__global__ __launch_bounds__(256)
void z6_csr_kernel(const int* __restrict__ off, const int* __restrict__ srt,
                   const float* __restrict__ asrc, const float* __restrict__ adst,
                   const __hip_bfloat16* __restrict__ hpA,
                   const __hip_bfloat16* __restrict__ hpB, __hip_bfloat16* zb) {
    __shared__ float sW[4][64 * 6];
    __shared__ int   sS[4][64];
    int t = threadIdx.x;
    int wslot = t >> 6;
    int wid = (blockIdx.x * 256 + t) >> 6;
    int d = __builtin_amdgcn_readfirstlane(wid);
    if (d >= NN) return;
    int lane = t & 63;
    bool act = lane < 40;
    int f = act ? lane : 0;
    const __hip_bfloat16* ht = (f < 32) ? hpA : hpB;
    const int sh = (f < 32) ? 5 : 3;
    const int fo = (f < 32) ? f : (f - 32);
    float4 bv0 = *reinterpret_cast<const float4*>(adst + (size_t)d * 8);
    float2 bv1 = *reinterpret_cast<const float2*>(adst + (size_t)d * 8 + 4);
    int jb = off[d], je = off[d + 1];
    float acc[6], ds[6];
#pragma unroll
    for (int h = 0; h < 6; h++) { acc[h] = 0.f; ds[h] = 0.f; }
    for (int c0 = jb; c0 < je; c0 += 64) {
        int cnt = je - c0; if (cnt > 64) cnt = 64;
        if (lane < cnt) {   // phase A
            int s = srt[c0 + lane];
            sS[wslot][lane] = s;
            float4 a0 = *reinterpret_cast<const float4*>(asrc + (size_t)s * 8);
            float2 a1 = *reinterpret_cast<const float2*>(asrc + (size_t)s * 8 + 4);
            float* wp = &sW[wslot][lane * 6];
            *reinterpret_cast<float4*>(wp) = make_float4(
                __expf(lrelu(a0.x + bv0.x)), __expf(lrelu(a0.y + bv0.y)),
                __expf(lrelu(a0.z + bv0.z)), __expf(lrelu(a0.w + bv0.w)));
            *reinterpret_cast<float2*>(wp + 4) = make_float2(
                __expf(lrelu(a1.x + bv1.x)), __expf(lrelu(a1.y + bv1.y)));
        }
        int j = 0;          // phase B (round-10 pairing)
        for (; j + 1 < cnt; j += 2) {
            int s0 = sS[wslot][j], s1 = sS[wslot][j + 1];
            float hv0 = __bfloat162float(ht[((size_t)s0 << sh) + fo]);
            float hv1 = __bfloat162float(ht[((size_t)s1 << sh) + fo]);
            const float* wp = &sW[wslot][j * 6];
#pragma unroll
            for (int h = 0; h < 6; h++) {
                float w0 = wp[h], w1 = wp[6 + h];
                acc[h] += w0 * hv0; acc[h] += w1 * hv1;
                ds[h] += w0 + w1;
            }
        }
        for (; j < cnt; ++j) {
            int s = sS[wslot][j];
            float hv = __bfloat162float(ht[((size_t)s << sh) + fo]);
            const float* wp = &sW[wslot][j * 6];
#pragma unroll
            for (int h = 0; h < 6; h++) {
                acc[h] += wp[h] * hv;
                ds[h] += wp[h];
            }
        }
    }
    if (act) {
#pragma unroll
        for (int h = 0; h < 6; h++)
            zb[(size_t)d * 288 + h * 40 + f] =
                __float2bfloat16(acc[h] / ds[h] * (1.0f / 6.0f));
    }
}

// ---------------- MFMA GEMM: out[100000x121] = A[100000x288]@B[288x128] + bias
__global__ __launch_bounds__(256)
void zgemm_mfma_kernel(const __hip_bfloat16* __restrict__ Ab,
                       const __hip_bfloat16* __restrict__ Bf,
                       const float* __restrict__ b3, const float* __restrict__ lb3,
                       float* __restrict__ out) {
    const int t = threadIdx.x;
    const int lane = t & 63, w = t >> 6;
    const int wr = w & 1, wc = w >> 1;
    const int n0 = blockIdx.x * 128;
    const short* As = (const short*)Ab;
    const short* Bs = (const short*)Bf;

    f32x4 acc[4][4];
#pragma unroll
    for (int i = 0; i < 4; i++)
#pragma unroll
        for (int j = 0; j < 4; j++) acc[i][j] = (f32x4){0.f, 0.f, 0.f, 0.f};

    const int arow = n0 + wr * 64 + (lane & 15);
    const int koff = (lane >> 4) * 8;

    for (int kk = 0; kk < 9; kk++) {
        bf16x8 af[4], bfr[4];
#pragma unroll
        for (int i = 0; i < 4; i++) {
            int r = arow + i * 16; if (r > NN - 1) r = NN - 1;
            af[i] = *(const bf16x8*)(As + (size_t)r * 288 + kk * 32 + koff);
        }
#pragma unroll
        for (int j = 0; j < 4; j++) {
            int ct = wc * 4 + j;
            bfr[j] = *(const bf16x8*)(Bs + (((size_t)kk * 8 + ct) * 64 + lane) * 8);
        }
#pragma unroll
        for (int i = 0; i < 4; i++)
#pragma unroll
            for (int j = 0; j < 4; j++)
                acc[i][j] = __builtin_amdgcn_mfma_f32_16x16x32_bf16(af[i], bfr[j], acc[i][j], 0, 0, 0);
    }

    const int c_base = wc * 64 + (lane & 15);
    const int r_quad = (lane >> 4) * 4;
#pragma unroll
    for (int j = 0; j < 4; j++) {
        int c = c_base + j * 16;
        if (c >= COUT) continue;
        float bias = b3[c] + lb3[c];
#pragma unroll
        for (int i = 0; i < 4; i++) {
            int nb = n0 + wr * 64 + i * 16 + r_quad;
#pragma unroll
            for (int q = 0; q < 4; q++) {
                int n = nb + q;
                if (n < NN) out[(size_t)n * COUT + c] = acc[i][j][q] + bias;
            }
        }
    }
}

extern "C" void kernel_launch(void* const* d_in, const int* in_sizes, int n_in,
                              void* d_out, int out_size, void* d_ws, size_t ws_size,
                              hipStream_t stream) {
    const float* x   = (const float*)d_in[0];
    const int*   ei  = (const int*)d_in[1];
    const float* W1  = (const float*)d_in[2];
    const float* as1 = (const float*)d_in[3];
    const float* ad1 = (const float*)d_in[4];
    const float* b1  = (const float*)d_in[5];
    const float* lw1 = (const float*)d_in[6];
    const float* lb1 = (const float*)d_in[7];
    const float* W2  = (const float*)d_in[8];
    const float* as2 = (const float*)d_in[9];
    const float* ad2 = (const float*)d_in[10];
    const float* b2  = (const float*)d_in[11];
    const float* lw2 = (const float*)d_in[12];
    const float* lb2 = (const float*)d_in[13];
    const float* W3  = (const float*)d_in[14];
    const float* as3 = (const float*)d_in[15];
    const float* ad3 = (const float*)d_in[16];
    const float* b3  = (const float*)d_in[17];
    const float* lw3 = (const float*)d_in[18];
    const float* lb3 = (const float*)d_in[19];
    float* out = (float*)d_out;
    float* ws  = (float*)d_ws;

    const int* esrc = ei;
    const int* edst = ei + NE;

    // ---- workspace layout (floats unless noted) ----
    // [0, 3.2M)      xwA (layers 1/2)  | hpA (bf16, 3.2M bf16) layer 3
    // [1.6M, 2.0M)                     | hpB (bf16, 0.8M bf16) layer 3
    // [3.2M, 4.0M)   xwB (layers 1/2)
    // [4M, 8M)       agg
    // [8M, 8.8M)     asrc ; [8.8M, 9.6M) adst ; [9.6M,...) Bc, Bf
    // [9.628M, 24.028M) zb (bf16)
    // [24.028M, ...) CSR ints
    float* xwA  = ws;
    float* xwB  = ws + 3200000;
    float* agg  = ws + 4000000;
    float* asrc = ws + 8000000;
    float* adst = ws + 8800000;
    float* Bc   = ws + 9600000;
    __hip_bfloat16* Bf = (__hip_bfloat16*)(ws + 9608000);
    __hip_bfloat16* zb = (__hip_bfloat16*)(ws + 9628000);
    __hip_bfloat16* hpA = (__hip_bfloat16*)ws;             // aliases xwA (layer 3)
    __hip_bfloat16* hpB = (__hip_bfloat16*)(ws + 1600000); // aliases xwA tail (layer 3)
    int* ib     = (int*)(ws + 24028000);
    int* deg    = ib;                 // 100,352
    int* off    = ib + 100352;        // 100,001 (+pad)
    int* bcnt   = ib + 200704;        // 128
    int* boff   = ib + 200832;        // 129
    int* bcur   = ib + 200992;        // 128
    int* bsum   = ib + 300704;        // 512
    int* bscan  = ib + 301216;        // 512
    int* sorted = ib + 301728;        // 1,700,000 -> ends 2,001,728
    int* ebuf   = ib + 2001728;       // 1,600,000 -> ends 3,601,728

    const int nodeBlocks = (NN + 255) / 256;       // 391
    const int binBlocks  = (NE + EPB - 1) / EPB;   // 196
    const int waveBlocks = NN / 4;                 // 25000
    const int featBlocks = (NN + 63) / 64;         // 1563 (64 rows/block)

    // ---- bucketed CSR build ----
    zero_bcnt_kernel<<<1, 256, 0, stream>>>(bcnt);
    bin_count_kernel<<<binBlocks, 256, 0, stream>>>(edst, bcnt);
    bin_scan_kernel<<<1, 256, 0, stream>>>(bcnt, boff, bcur);
    bin_place_kernel<<<binBlocks, 256, 0, stream>>>(esrc, edst, bcur, ebuf);
    bucket_deg_kernel<<<NB, 256, 0, stream>>>(boff, ebuf, deg);
    scan_block_kernel<<<nodeBlocks, 256, 0, stream>>>(deg, off, bsum);
    scan_bsum_kernel<<<1, 256, 0, stream>>>(bsum, bscan, nodeBlocks);
    place_kernel<<<nodeBlocks, 256, 0, stream>>>(off, bscan, sorted);
    bucket_scatter_kernel<<<NB, 256, 0, stream>>>(boff, ebuf, off, sorted);

    // ---- layer 1 ----
    fold_B12_kernel<<<(FIN * 88 + 255) / 256, 256, 0, stream>>>(W1, lw1, as1, ad1, Bc, FIN);
    feature12_kernel<FIN><<<featBlocks, 256, 0, stream>>>(x, Bc, b1, lb1, xwA, xwB, agg, asrc, adst);
    agg4_csr_kernel<<<waveBlocks, 256, 0, stream>>>(off, sorted, asrc, adst, xwA, xwB, agg);

    // ---- layer 2 ----
    fold_B12_kernel<<<(HID * 88 + 255) / 256, 256, 0, stream>>>(W2, lw2, as2, ad2, Bc, HID);
    feature12_kernel<HID><<<featBlocks, 256, 0, stream>>>(agg, Bc, b2, lb2, xwA, xwB, agg, asrc, adst);
    agg4_csr_kernel<<<waveBlocks, 256, 0, stream>>>(off, sorted, asrc, adst, xwA, xwB, agg);

    // ---- layer 3 ----
    fold_B3_kernel<<<(40 * 12 + 255) / 256, 256, 0, stream>>>(W3, as3, ad3, Bc);
    fold_Bf_kernel<<<(9 * 8 * 64 * 8 + 255) / 256, 256, 0, stream>>>(W3, lw3, Bf);
    feature3_kernel<<<nodeBlocks, 256, 0, stream>>>(agg, Bc, asrc, adst, zb, hpA, hpB);
    z6_csr_kernel<<<waveBlocks, 256, 0, stream>>>(off, sorted, asrc, adst, hpA, hpB, zb);
    zgemm_mfma_kernel<<<(NN + 127) / 128, 256, 0, stream>>>(zb, Bf, b3, lb3, out);
}

// Round 10
// 537.436 us; speedup vs baseline: 1.1409x; 1.0047x over previous
//
#include <hip/hip_runtime.h>
#include <hip/hip_bf16.h>
#include <math.h>

// GAT x3 on N=100000 nodes, E=1600000 edges (+ self loops).
// Round 15: bf16 gather tables for layers 1/2. agg4 was gathering fp32 xw
// rows (128B+32B = ~4 random lines/edge incl. asrc); z6's hp tables proved
// the bf16 64B+16B layout (~2.3 lines/edge). xw -> xbA[node][32] +
// xbB[node][8] bf16, exactly mirroring layer 3's hpA/hpB (same buffers,
// reused across layers). Quantizes only the neighbor-message features of
// layers 1/2 (scores/weights/denominator/self path stay fp32) - the same
// quantization layer 3 already applies. z6 left at its measured plateau
// (83-91us across r11-r14 variants; compulsory-traffic bound).
// (R14: split aligned tables; R10: fused weights in LDS; R9: feature12
// LDS-B; R8: bucketed CSR build.)

#define NN 100000
#define NE 1600000
#define NT (NE + NN)
#define FIN 50
#define HID 40
#define COUT 121

#define NB 128           // buckets
#define NPB 782          // nodes per bucket (128*782 = 100096 >= NN)
#define EPB 8192         // edges per bin block

typedef __attribute__((ext_vector_type(8))) short bf16x8;
typedef __attribute__((ext_vector_type(4))) float f32x4;

__device__ __forceinline__ float lrelu(float x) { return fmaxf(x, 0.2f * x); }
__device__ __forceinline__ float elu1(float x)  { return x > 0.f ? x : __expf(x) - 1.f; }
__device__ __forceinline__ unsigned pkbf(float a, float b) {
    __hip_bfloat16 ha = __float2bfloat16(a), hb = __float2bfloat16(b);
    return ((unsigned)*reinterpret_cast<unsigned short*>(&hb) << 16) |
           *reinterpret_cast<unsigned short*>(&ha);
}

// ---------------- bucketed CSR build ----------------
__global__ __launch_bounds__(256)
void zero_bcnt_kernel(int* __restrict__ bcnt) {
    int t = threadIdx.x;
    if (t < NB) bcnt[t] = 0;
}

__global__ __launch_bounds__(256)
void bin_count_kernel(const int* __restrict__ edst, int* __restrict__ bcnt) {
    __shared__ int h[NB];
    int t = threadIdx.x;
    if (t < NB) h[t] = 0;
    __syncthreads();
    int e0 = blockIdx.x * EPB;
    for (int q = 0; q < EPB; q += 256) {
        int e = e0 + q + t;
        if (e < NE) atomicAdd(&h[edst[e] / NPB], 1);
    }
    __syncthreads();
    if (t < NB && h[t]) atomicAdd(&bcnt[t], h[t]);
}

__global__ __launch_bounds__(256)
void bin_scan_kernel(const int* __restrict__ bcnt, int* __restrict__ boff,
                     int* __restrict__ bcur) {
    __shared__ int s[NB];
    int t = threadIdx.x;
    if (t < NB) s[t] = bcnt[t];
    __syncthreads();
    if (t == 0) {
        int run = 0;
        for (int i = 0; i < NB; i++) { int c = s[i]; s[i] = run; run += c; }
        boff[NB] = run;   // == NE
    }
    __syncthreads();
    if (t < NB) { boff[t] = s[t]; bcur[t] = s[t]; }
}

// Each block claims a contiguous chunk per bucket, then writes packed records
// src | (dst_in_bucket << 17) into its exclusive chunk (dense, short window).
__global__ __launch_bounds__(256)
void bin_place_kernel(const int* __restrict__ esrc, const int* __restrict__ edst,
                      int* __restrict__ bcur, int* __restrict__ ebuf) {
    __shared__ int h[NB], base[NB], lcur[NB];
    int t = threadIdx.x;
    if (t < NB) h[t] = 0;
    __syncthreads();
    int e0 = blockIdx.x * EPB;
    for (int q = 0; q < EPB; q += 256) {
        int e = e0 + q + t;
        if (e < NE) atomicAdd(&h[edst[e] / NPB], 1);
    }
    __syncthreads();
    if (t < NB) {
        int c = h[t];
        base[t] = c ? atomicAdd(&bcur[t], c) : 0;
        lcur[t] = 0;
    }
    __syncthreads();
    for (int q = 0; q < EPB; q += 256) {
        int e = e0 + q + t;
        if (e < NE) {
            int d = edst[e], s = esrc[e];
            int b = d / NPB;
            int r = atomicAdd(&lcur[b], 1);
            ebuf[base[b] + r] = s | ((d - b * NPB) << 17);
        }
    }
}

// One block per bucket: per-node degree via LDS histogram.
__global__ __launch_bounds__(256)
void bucket_deg_kernel(const int* __restrict__ boff, const int* __restrict__ ebuf,
                       int* __restrict__ deg) {
    __shared__ int h[NPB];
    int b = blockIdx.x, t = threadIdx.x;
    for (int i = t; i < NPB; i += 256) h[i] = 0;
    __syncthreads();
    int jb = boff[b], je = boff[b + 1];
    for (int j = jb + t; j < je; j += 256) atomicAdd(&h[ebuf[j] >> 17], 1);
    __syncthreads();
    int n0 = b * NPB;
    for (int i = t; i < NPB; i += 256) {
        int n = n0 + i;
        if (n < NN) deg[n] = h[i] + 1;   // +1 self loop
    }
}

// One block per bucket: replay records with LDS cursors; sorted_src writes
// land in this block's exclusive CSR range (L2-local, written back once).
__global__ __launch_bounds__(256)
void bucket_scatter_kernel(const int* __restrict__ boff, const int* __restrict__ ebuf,
                           const int* __restrict__ off, int* __restrict__ sorted_src) {
    __shared__ int lcur[NPB];
    int b = blockIdx.x, t = threadIdx.x;
    int n0 = b * NPB;
    for (int i = t; i < NPB; i += 256) {
        int n = n0 + i;
        lcur[i] = (n < NN) ? off[n] + 1 : 0;   // +1: self loop occupies slot 0
    }
    __syncthreads();
    int jb = boff[b], je = boff[b + 1];
    for (int j = jb + t; j < je; j += 256) {
        int rec = ebuf[j];
        int p = atomicAdd(&lcur[rec >> 17], 1);
        sorted_src[p] = rec & 0x1FFFF;
    }
}

// ---------------- node-offset scan ----------------
__global__ __launch_bounds__(256)
void scan_block_kernel(const int* __restrict__ deg, int* __restrict__ off,
                       int* __restrict__ bsum) {
    __shared__ int s[256];
    int t = threadIdx.x, b = blockIdx.x, i = b * 256 + t;
    int v = (i < NN) ? deg[i] : 0;
    s[t] = v; __syncthreads();
#pragma unroll
    for (int o = 1; o < 256; o <<= 1) {
        int x = (t >= o) ? s[t - o] : 0;
        __syncthreads();
        s[t] += x;
        __syncthreads();
    }
    if (i < NN) off[i] = s[t] - v;
    if (t == 255) bsum[b] = s[255];
}

__global__ __launch_bounds__(256)
void scan_bsum_kernel(const int* __restrict__ bsum, int* __restrict__ bscan, int nb) {
    __shared__ int s[256];
    int t = threadIdx.x;
    int carry = 0;
    int nc = (nb + 255) / 256;
    for (int c = 0; c < nc; c++) {
        int i = c * 256 + t;
        int v = (i < nb) ? bsum[i] : 0;
        s[t] = v; __syncthreads();
#pragma unroll
        for (int o = 1; o < 256; o <<= 1) {
            int x = (t >= o) ? s[t - o] : 0;
            __syncthreads();
            s[t] += x;
            __syncthreads();
        }
        if (i < nb) bscan[i] = carry + s[t] - v;
        carry += s[255];
        __syncthreads();
    }
}

__global__ __launch_bounds__(256)
void place_kernel(int* __restrict__ off, const int* __restrict__ bscan,
                  int* __restrict__ sorted_src) {
    int i = blockIdx.x * 256 + threadIdx.x;
    if (i == 0) off[NN] = NT;
    if (i < NN) {
        int o = off[i] + bscan[i >> 8];
        off[i] = o;
        sorted_src[o] = i;   // self loop first
    }
}

// ---------------- fold weight blocks ----------------
__global__ __launch_bounds__(256)
void fold_B12_kernel(const float* __restrict__ W, const float* __restrict__ lw,
                     const float* __restrict__ as_, const float* __restrict__ ad_,
                     float* __restrict__ B, int F) {
    int t = blockIdx.x * 256 + threadIdx.x;
    if (t >= F * 88) return;
    int f = t / 88, j = t - f * 88;
    float v = 0.f;
    if (j < 40) v = W[f * 40 + j];
    else if (j < 80) v = lw[f * 40 + (j - 40)];
    else if (j < 84) {
        int h = j - 80; float s = 0.f;
        for (int d = 0; d < 10; d++) s += W[f * 40 + h * 10 + d] * as_[h * 10 + d];
        v = s;
    } else {
        int h = j - 84; float s = 0.f;
        for (int d = 0; d < 10; d++) s += W[f * 40 + h * 10 + d] * ad_[h * 10 + d];
        v = s;
    }
    B[t] = v;
}

__global__ __launch_bounds__(256)
void fold_B3_kernel(const float* __restrict__ W3, const float* __restrict__ as3,
                    const float* __restrict__ ad3, float* __restrict__ B) {
    int t = blockIdx.x * 256 + threadIdx.x;
    if (t >= 40 * 12) return;
    int f = t / 12, k = t - f * 12;
    float s = 0.f;
    if (k < 6) {
        int h = k;
        for (int c = 0; c < COUT; c++) s += W3[f * 726 + h * COUT + c] * as3[h * COUT + c];
    } else {
        int h = k - 6;
        for (int c = 0; c < COUT; c++) s += W3[f * 726 + h * COUT + c] * ad3[h * COUT + c];
    }
    B[t] = s;
}

// Fold W3/lw3 into bf16 MFMA B-fragment order.
__global__ __launch_bounds__(256)
void fold_Bf_kernel(const float* __restrict__ W3, const float* __restrict__ lw3,
                    __hip_bfloat16* __restrict__ Bf) {
    int t = blockIdx.x * 256 + threadIdx.x;
    if (t >= 9 * 8 * 64 * 8) return;
    int j = t & 7, lane = (t >> 3) & 63, ct = (t >> 9) & 7, kt = t >> 12;
    int k = kt * 32 + (lane >> 4) * 8 + j;
    int c = ct * 16 + (lane & 15);
    float v = 0.f;
    if (c < COUT) {
        if (k < 240) {
            int h = k / 40, f = k - h * 40;
            v = W3[f * 726 + h * COUT + c];
        } else if (k < 280) {
            int f = k - 240;
            v = lw3[f * COUT + c];
        }
    }
    Bf[t] = __float2bfloat16(v);
}

// ---------------- fused feature GEMM for layers 1/2 ----------------
// xw messages stored as bf16 split tables: f<32 -> xbA (64B aligned rows),
// f in [32,40) -> xbB (16B rows). agg/asrc/adst stay fp32.
template <int F>
__global__ __launch_bounds__(256)
void feature12_kernel(const float* __restrict__ A, const float* __restrict__ B,
                      const float* __restrict__ bias, const float* __restrict__ lbias,
                      __hip_bfloat16* __restrict__ xbA, __hip_bfloat16* __restrict__ xbB,
                      float* __restrict__ agg,
                      float* __restrict__ asrc, float* __restrict__ adst) {
    __shared__ float sB[F * 88];
    const int t = threadIdx.x;
    for (int i = t; i < F * 88; i += 256) sB[i] = B[i];

    const int lane = t & 63;
    const int p = __builtin_amdgcn_readfirstlane(t >> 6);
    const int r = blockIdx.x * 64 + lane;
    const bool valid = r < NN;
    const int rr = valid ? r : NN - 1;

    float a[F];
    if (F % 4 == 0) {
        const float4* A4 = reinterpret_cast<const float4*>(A + (size_t)rr * F);
#pragma unroll
        for (int q = 0; q < F / 4; q++) {
            float4 v = A4[q];
            a[4 * q] = v.x; a[4 * q + 1] = v.y; a[4 * q + 2] = v.z; a[4 * q + 3] = v.w;
        }
    } else {
        const float2* A2 = reinterpret_cast<const float2*>(A + (size_t)rr * F);
#pragma unroll
        for (int q = 0; q < F / 2; q++) {
            float2 v = A2[q];
            a[2 * q] = v.x; a[2 * q + 1] = v.y;
        }
        if (F & 1) a[F - 1] = A[(size_t)rr * F + F - 1];
    }
    __syncthreads();

    for (int g = p; g < 11; g += 4) {
        const int j0 = g * 8;
        float acc[8];
#pragma unroll
        for (int k = 0; k < 8; k++) acc[k] = 0.f;
#pragma unroll
        for (int f = 0; f < F; f++) {
            float av = a[f];
            float4 b0 = *reinterpret_cast<const float4*>(&sB[f * 88 + j0]);
            float4 b1 = *reinterpret_cast<const float4*>(&sB[f * 88 + j0 + 4]);
            acc[0] += av * b0.x; acc[1] += av * b0.y;
            acc[2] += av * b0.z; acc[3] += av * b0.w;
            acc[4] += av * b1.x; acc[5] += av * b1.y;
            acc[6] += av * b1.z; acc[7] += av * b1.w;
        }
        if (!valid) continue;
        if (j0 < 32) {
            uint4 v;
            v.x = pkbf(acc[0], acc[1]); v.y = pkbf(acc[2], acc[3]);
            v.z = pkbf(acc[4], acc[5]); v.w = pkbf(acc[6], acc[7]);
            *reinterpret_cast<uint4*>(&xbA[(size_t)r * 32 + j0]) = v;
        } else if (j0 < 40) {   // j0 == 32
            uint4 v;
            v.x = pkbf(acc[0], acc[1]); v.y = pkbf(acc[2], acc[3]);
            v.z = pkbf(acc[4], acc[5]); v.w = pkbf(acc[6], acc[7]);
            *reinterpret_cast<uint4*>(&xbB[(size_t)r * 8]) = v;
        } else if (j0 < 80) {
            int j = j0 - 40;
#pragma unroll
            for (int k = 0; k < 8; k++) acc[k] += bias[j + k] + lbias[j + k];
            *reinterpret_cast<float4*>(agg + (size_t)r * 40 + j) =
                make_float4(acc[0], acc[1], acc[2], acc[3]);
            *reinterpret_cast<float4*>(agg + (size_t)r * 40 + j + 4) =
                make_float4(acc[4], acc[5], acc[6], acc[7]);
        } else {
            *reinterpret_cast<float4*>(asrc + (size_t)r * 8) =
                make_float4(acc[0], acc[1], acc[2], acc[3]);
            *reinterpret_cast<float4*>(adst + (size_t)r * 8) =
                make_float4(acc[4], acc[5], acc[6], acc[7]);
        }
    }
}

// ---------------- layer 3 scores + bf16 h2 copies (zb + split hpA/hpB) ------
__global__ __launch_bounds__(256)
void feature3_kernel(const float* __restrict__ A, const float* __restrict__ B,
                     float* __restrict__ asrc, float* __restrict__ adst,
                     __hip_bfloat16* __restrict__ zb,
                     __hip_bfloat16* __restrict__ hpA, __hip_bfloat16* __restrict__ hpB) {
    int r = blockIdx.x * 256 + threadIdx.x;
    if (r >= NN) return;
    float a[40];
    const float4* A4 = reinterpret_cast<const float4*>(A + (size_t)r * 40);
#pragma unroll
    for (int q = 0; q < 10; q++) {
        float4 v = A4[q];
        a[4 * q] = v.x; a[4 * q + 1] = v.y; a[4 * q + 2] = v.z; a[4 * q + 3] = v.w;
    }
    __hip_bfloat16* zr = zb + (size_t)r * 288 + 240;
    __hip_bfloat16* ha = hpA + (size_t)r * 32;
    __hip_bfloat16* hb = hpB + (size_t)r * 8;
#pragma unroll
    for (int f = 0; f < 40; f++) {
        __hip_bfloat16 v = __float2bfloat16(a[f]);
        zr[f] = v;
        if (f < 32) ha[f] = v; else hb[f - 32] = v;
    }
#pragma unroll
    for (int f = 40; f < 48; f++) zr[f] = __float2bfloat16(0.f);

    float acc[12];
#pragma unroll
    for (int k = 0; k < 12; k++) acc[k] = 0.f;
#pragma unroll
    for (int f = 0; f < 40; f++) {
        float av = a[f];
#pragma unroll
        for (int k = 0; k < 12; k++) acc[k] += av * B[f * 12 + k];
    }
    *reinterpret_cast<float4*>(asrc + (size_t)r * 8) = make_float4(acc[0], acc[1], acc[2], acc[3]);
    *reinterpret_cast<float2*>(asrc + (size_t)r * 8 + 4) = make_float2(acc[4], acc[5]);
    *reinterpret_cast<float4*>(adst + (size_t)r * 8) = make_float4(acc[6], acc[7], acc[8], acc[9]);
    *reinterpret_cast<float2*>(adst + (size_t)r * 8 + 4) = make_float2(acc[10], acc[11]);
}

// ---------------- CSR aggregation, H=4, fused weights (LDS), fused ELU ------
// Round-10 structure. bf16 gather tables: lane f<32 reads xbA[s*32+f]
// (64B-aligned rows = ONE line/edge), f>=32 reads xbB[s*8+f-32] (1.6MB).
__global__ __launch_bounds__(256)
void agg4_csr_kernel(const int* __restrict__ off, const int* __restrict__ srt,
                     const float* __restrict__ asrc, const float* __restrict__ adst,
                     const __hip_bfloat16* __restrict__ xbA,
                     const __hip_bfloat16* __restrict__ xbB, float* agg) {
    __shared__ float sW[4][64 * 4];
    __shared__ int   sS[4][64];
    int t = threadIdx.x;
    int wslot = t >> 6;
    int wid = (blockIdx.x * 256 + t) >> 6;
    int d = __builtin_amdgcn_readfirstlane(wid);
    if (d >= NN) return;
    int lane = t & 63;
    bool act = lane < 40;
    int f = act ? lane : 0;
    int hh = f / 10;
    const __hip_bfloat16* xt = (f < 32) ? xbA : xbB;
    const int sh = (f < 32) ? 5 : 3;
    const int fo = (f < 32) ? f : (f - 32);
    float4 bv = *reinterpret_cast<const float4*>(adst + (size_t)d * 8);
    int jb = off[d], je = off[d + 1];
    float acc = 0.f, ds = 0.f;
    for (int c0 = jb; c0 < je; c0 += 64) {
        int cnt = je - c0; if (cnt > 64) cnt = 64;
        if (lane < cnt) {   // phase A: one lane per edge
            int s = srt[c0 + lane];
            sS[wslot][lane] = s;
            float4 a = *reinterpret_cast<const float4*>(asrc + (size_t)s * 8);
            float4 w;
            w.x = __expf(lrelu(a.x + bv.x));
            w.y = __expf(lrelu(a.y + bv.y));
            w.z = __expf(lrelu(a.z + bv.z));
            w.w = __expf(lrelu(a.w + bv.w));
            *reinterpret_cast<float4*>(&sW[wslot][lane * 4]) = w;
        }
        int j = 0;          // phase B: FMA loop (round-10 order)
        for (; j + 3 < cnt; j += 4) {
            int s0 = sS[wslot][j], s1 = sS[wslot][j + 1];
            int s2 = sS[wslot][j + 2], s3 = sS[wslot][j + 3];
            float w0 = sW[wslot][(j + 0) * 4 + hh];
            float w1 = sW[wslot][(j + 1) * 4 + hh];
            float w2 = sW[wslot][(j + 2) * 4 + hh];
            float w3 = sW[wslot][(j + 3) * 4 + hh];
            float x0 = __bfloat162float(xt[((size_t)s0 << sh) + fo]);
            float x1 = __bfloat162float(xt[((size_t)s1 << sh) + fo]);
            float x2 = __bfloat162float(xt[((size_t)s2 << sh) + fo]);
            float x3 = __bfloat162float(xt[((size_t)s3 << sh) + fo]);
            acc += w0 * x0; acc += w1 * x1; acc += w2 * x2; acc += w3 * x3;
            ds += (w0 + w1) + (w2 + w3);
        }
        for (; j < cnt; ++j) {
            int s = sS[wslot][j];
            float w = sW[wslot][j * 4 + hh];
            acc += w * __bfloat162float(xt[((size_t)s << sh) + fo]);
            ds += w;
        }
    }
    if (act) {
        float v = agg[(size_t)d * 40 + f] + acc / ds;
        agg[(size_t)d * 40 + f] = elu1(v);   // ELU fused (layers 1/2 only)
    }
}

// ---------------- CSR aggregation, H=6 -> bf16 z, fused weights (LDS) -------
// Round-10 structure. Gather table split: lane f<32 reads hpA[s*32+f]
// (64B-aligned rows = ONE line/edge), f>=32 reads hpB[s*8+f-32] (1.6MB).
__global__ __launch_bounds__(256)
void z6_csr_kernel(const int* __restrict__ off, const int* __restrict__ srt,
                   const float* __restrict__ asrc, const float* __restrict__ adst,
                   const __hip_bfloat16* __restrict__ hpA,
                   const __hip_bfloat16* __restrict__ hpB, __hip_bfloat16* zb) {
    __shared__ float sW[4][64 * 6];
    __shared__ int   sS[4][64];
    int t = threadIdx.x;
    int wslot = t >> 6;
    int wid = (blockIdx.x * 256 + t) >> 6;
    int d = __builtin_amdgcn_readfirstlane(wid);
    if (d >= NN) return;
    int lane = t & 63;
    bool act = lane < 40;
    int f = act ? lane : 0;
    const __hip_bfloat16* ht = (f < 32) ? hpA : hpB;
    const int sh = (f < 32) ? 5 : 3;
    const int fo = (f < 32) ? f : (f - 32);
    float4 bv0 = *reinterpret_cast<const float4*>(adst + (size_t)d * 8);
    float2 bv1 = *reinterpret_cast<const float2*>(adst + (size_t)d * 8 + 4);
    int jb = off[d], je = off[d + 1];
    float acc[6], ds[6];
#pragma unroll
    for (int h = 0; h < 6; h++) { acc[h] = 0.f; ds[h] = 0.f; }
    for (int c0 = jb; c0 < je; c0 += 64) {
        int cnt = je - c0; if (cnt > 64) cnt = 64;
        if (lane < cnt) {   // phase A
            int s = srt[c0 + lane];
            sS[wslot][lane] = s;
            float4 a0 = *reinterpret_cast<const float4*>(asrc + (size_t)s * 8);
            float2 a1 = *reinterpret_cast<const float2*>(asrc + (size_t)s * 8 + 4);
            float* wp = &sW[wslot][lane * 6];
            *reinterpret_cast<float4*>(wp) = make_float4(
                __expf(lrelu(a0.x + bv0.x)), __expf(lrelu(a0.y + bv0.y)),
                __expf(lrelu(a0.z + bv0.z)), __expf(lrelu(a0.w + bv0.w)));
            *reinterpret_cast<float2*>(wp + 4) = make_float2(
                __expf(lrelu(a1.x + bv1.x)), __expf(lrelu(a1.y + bv1.y)));
        }
        int j = 0;          // phase B (round-10 pairing)
        for (; j + 1 < cnt; j += 2) {
            int s0 = sS[wslot][j], s1 = sS[wslot][j + 1];
            float hv0 = __bfloat162float(ht[((size_t)s0 << sh) + fo]);
            float hv1 = __bfloat162float(ht[((size_t)s1 << sh) + fo]);
            const float* wp = &sW[wslot][j * 6];
#pragma unroll
            for (int h = 0; h < 6; h++) {
                float w0 = wp[h], w1 = wp[6 + h];
                acc[h] += w0 * hv0; acc[h] += w1 * hv1;
                ds[h] += w0 + w1;
            }
        }
        for (; j < cnt; ++j) {
            int s = sS[wslot][j];
            float hv = __bfloat162float(ht[((size_t)s << sh) + fo]);
            const float* wp = &sW[wslot][j * 6];
#pragma unroll
            for (int h = 0; h < 6; h++) {
                acc[h] += wp[h] * hv;
                ds[h] += wp[h];
            }
        }
    }
    if (act) {
#pragma unroll
        for (int h = 0; h < 6; h++)
            zb[(size_t)d * 288 + h * 40 + f] =
                __float2bfloat16(acc[h] / ds[h] * (1.0f / 6.0f));
    }
}

// ---------------- MFMA GEMM: out[100000x121] = A[100000x288]@B[288x128] + bias
__global__ __launch_bounds__(256)
void zgemm_mfma_kernel(const __hip_bfloat16* __restrict__ Ab,
                       const __hip_bfloat16* __restrict__ Bf,
                       const float* __restrict__ b3, const float* __restrict__ lb3,
                       float* __restrict__ out) {
    const int t = threadIdx.x;
    const int lane = t & 63, w = t >> 6;
    const int wr = w & 1, wc = w >> 1;
    const int n0 = blockIdx.x * 128;
    const short* As = (const short*)Ab;
    const short* Bs = (const short*)Bf;

    f32x4 acc[4][4];
#pragma unroll
    for (int i = 0; i < 4; i++)
#pragma unroll
        for (int j = 0; j < 4; j++) acc[i][j] = (f32x4){0.f, 0.f, 0.f, 0.f};

    const int arow = n0 + wr * 64 + (lane & 15);
    const int koff = (lane >> 4) * 8;

    for (int kk = 0; kk < 9; kk++) {
        bf16x8 af[4], bfr[4];
#pragma unroll
        for (int i = 0; i < 4; i++) {
            int r = arow + i * 16; if (r > NN - 1) r = NN - 1;
            af[i] = *(const bf16x8*)(As + (size_t)r * 288 + kk * 32 + koff);
        }
#pragma unroll
        for (int j = 0; j < 4; j++) {
            int ct = wc * 4 + j;
            bfr[j] = *(const bf16x8*)(Bs + (((size_t)kk * 8 + ct) * 64 + lane) * 8);
        }
#pragma unroll
        for (int i = 0; i < 4; i++)
#pragma unroll
            for (int j = 0; j < 4; j++)
                acc[i][j] = __builtin_amdgcn_mfma_f32_16x16x32_bf16(af[i], bfr[j], acc[i][j], 0, 0, 0);
    }

    const int c_base = wc * 64 + (lane & 15);
    const int r_quad = (lane >> 4) * 4;
#pragma unroll
    for (int j = 0; j < 4; j++) {
        int c = c_base + j * 16;
        if (c >= COUT) continue;
        float bias = b3[c] + lb3[c];
#pragma unroll
        for (int i = 0; i < 4; i++) {
            int nb = n0 + wr * 64 + i * 16 + r_quad;
#pragma unroll
            for (int q = 0; q < 4; q++) {
                int n = nb + q;
                if (n < NN) out[(size_t)n * COUT + c] = acc[i][j][q] + bias;
            }
        }
    }
}

extern "C" void kernel_launch(void* const* d_in, const int* in_sizes, int n_in,
                              void* d_out, int out_size, void* d_ws, size_t ws_size,
                              hipStream_t stream) {
    const float* x   = (const float*)d_in[0];
    const int*   ei  = (const int*)d_in[1];
    const float* W1  = (const float*)d_in[2];
    const float* as1 = (const float*)d_in[3];
    const float* ad1 = (const float*)d_in[4];
    const float* b1  = (const float*)d_in[5];
    const float* lw1 = (const float*)d_in[6];
    const float* lb1 = (const float*)d_in[7];
    const float* W2  = (const float*)d_in[8];
    const float* as2 = (const float*)d_in[9];
    const float* ad2 = (const float*)d_in[10];
    const float* b2  = (const float*)d_in[11];
    const float* lw2 = (const float*)d_in[12];
    const float* lb2 = (const float*)d_in[13];
    const float* W3  = (const float*)d_in[14];
    const float* as3 = (const float*)d_in[15];
    const float* ad3 = (const float*)d_in[16];
    const float* b3  = (const float*)d_in[17];
    const float* lw3 = (const float*)d_in[18];
    const float* lb3 = (const float*)d_in[19];
    float* out = (float*)d_out;
    float* ws  = (float*)d_ws;

    const int* esrc = ei;
    const int* edst = ei + NE;

    // ---- workspace layout (floats unless noted) ----
    // [0, 1.6M)      xbA (bf16, layers 1/2) | hpA (bf16, layer 3) - same slot
    // [1.6M, 2.0M)   xbB (bf16)             | hpB (bf16)          - same slot
    // [4M, 8M)       agg
    // [8M, 8.8M)     asrc ; [8.8M, 9.6M) adst ; [9.6M,...) Bc, Bf
    // [9.628M, 24.028M) zb (bf16)
    // [24.028M, ...) CSR ints
    __hip_bfloat16* xbA = (__hip_bfloat16*)ws;
    __hip_bfloat16* xbB = (__hip_bfloat16*)(ws + 1600000);
    float* agg  = ws + 4000000;
    float* asrc = ws + 8000000;
    float* adst = ws + 8800000;
    float* Bc   = ws + 9600000;
    __hip_bfloat16* Bf = (__hip_bfloat16*)(ws + 9608000);
    __hip_bfloat16* zb = (__hip_bfloat16*)(ws + 9628000);
    __hip_bfloat16* hpA = xbA;   // layer 3 reuses the same slots
    __hip_bfloat16* hpB = xbB;
    int* ib     = (int*)(ws + 24028000);
    int* deg    = ib;                 // 100,352
    int* off    = ib + 100352;        // 100,001 (+pad)
    int* bcnt   = ib + 200704;        // 128
    int* boff   = ib + 200832;        // 129
    int* bcur   = ib + 200992;        // 128
    int* bsum   = ib + 300704;        // 512
    int* bscan  = ib + 301216;        // 512
    int* sorted = ib + 301728;        // 1,700,000 -> ends 2,001,728
    int* ebuf   = ib + 2001728;       // 1,600,000 -> ends 3,601,728

    const int nodeBlocks = (NN + 255) / 256;       // 391
    const int binBlocks  = (NE + EPB - 1) / EPB;   // 196
    const int waveBlocks = NN / 4;                 // 25000
    const int featBlocks = (NN + 63) / 64;         // 1563 (64 rows/block)

    // ---- bucketed CSR build ----
    zero_bcnt_kernel<<<1, 256, 0, stream>>>(bcnt);
    bin_count_kernel<<<binBlocks, 256, 0, stream>>>(edst, bcnt);
    bin_scan_kernel<<<1, 256, 0, stream>>>(bcnt, boff, bcur);
    bin_place_kernel<<<binBlocks, 256, 0, stream>>>(esrc, edst, bcur, ebuf);
    bucket_deg_kernel<<<NB, 256, 0, stream>>>(boff, ebuf, deg);
    scan_block_kernel<<<nodeBlocks, 256, 0, stream>>>(deg, off, bsum);
    scan_bsum_kernel<<<1, 256, 0, stream>>>(bsum, bscan, nodeBlocks);
    place_kernel<<<nodeBlocks, 256, 0, stream>>>(off, bscan, sorted);
    bucket_scatter_kernel<<<NB, 256, 0, stream>>>(boff, ebuf, off, sorted);

    // ---- layer 1 ----
    fold_B12_kernel<<<(FIN * 88 + 255) / 256, 256, 0, stream>>>(W1, lw1, as1, ad1, Bc, FIN);
    feature12_kernel<FIN><<<featBlocks, 256, 0, stream>>>(x, Bc, b1, lb1, xbA, xbB, agg, asrc, adst);
    agg4_csr_kernel<<<waveBlocks, 256, 0, stream>>>(off, sorted, asrc, adst, xbA, xbB, agg);

    // ---- layer 2 ----
    fold_B12_kernel<<<(HID * 88 + 255) / 256, 256, 0, stream>>>(W2, lw2, as2, ad2, Bc, HID);
    feature12_kernel<HID><<<featBlocks, 256, 0, stream>>>(agg, Bc, b2, lb2, xbA, xbB, agg, asrc, adst);
    agg4_csr_kernel<<<waveBlocks, 256, 0, stream>>>(off, sorted, asrc, adst, xbA, xbB, agg);

    // ---- layer 3 ----
    fold_B3_kernel<<<(40 * 12 + 255) / 256, 256, 0, stream>>>(W3, as3, ad3, Bc);
    fold_Bf_kernel<<<(9 * 8 * 64 * 8 + 255) / 256, 256, 0, stream>>>(W3, lw3, Bf);
    feature3_kernel<<<nodeBlocks, 256, 0, stream>>>(agg, Bc, asrc, adst, zb, hpA, hpB);
    z6_csr_kernel<<<waveBlocks, 256, 0, stream>>>(off, sorted, asrc, adst, hpA, hpB, zb);
    zgemm_mfma_kernel<<<(NN + 127) / 128, 256, 0, stream>>>(zb, Bf, b3, lb3, out);
}

// Round 11
// 517.288 us; speedup vs baseline: 1.1853x; 1.0390x over previous
//
#include <hip/hip_runtime.h>
#include <hip/hip_bf16.h>
#include <math.h>

// GAT x3 on N=100000 nodes, E=1600000 edges (+ self loops).
// Round 16: kill the third gather line. agg4/z6 paid 3 random lines/edge:
// featA (64B) + featB line + fp32 asrc score row. Scores now ride as bf16
// INSIDE the featB row: xcB/hcB[node][16] bf16 (32B rows) = feats 32..39 in
// [0:8] + asrc scores in [8:12]/[8:14]. Phase-A score read and phase-B tail
// feature read hit the SAME line -> 2 lines/edge. fp32 asrc array dropped.
// Scores bf16: error ~6e-4, below the existing bf16 feature quantization.
// (R15: bf16 gather tables; R14: split aligned tables; R10: fused weights
// in LDS; R9: feature12 LDS-B; R8: bucketed CSR build.)

#define NN 100000
#define NE 1600000
#define NT (NE + NN)
#define FIN 50
#define HID 40
#define COUT 121

#define NB 128           // buckets
#define NPB 782          // nodes per bucket (128*782 = 100096 >= NN)
#define EPB 8192         // edges per bin block

typedef __attribute__((ext_vector_type(8))) short bf16x8;
typedef __attribute__((ext_vector_type(4))) float f32x4;

__device__ __forceinline__ float lrelu(float x) { return fmaxf(x, 0.2f * x); }
__device__ __forceinline__ float elu1(float x)  { return x > 0.f ? x : __expf(x) - 1.f; }
__device__ __forceinline__ unsigned pkbf(float a, float b) {
    __hip_bfloat16 ha = __float2bfloat16(a), hb = __float2bfloat16(b);
    return ((unsigned)*reinterpret_cast<unsigned short*>(&hb) << 16) |
           *reinterpret_cast<unsigned short*>(&ha);
}
__device__ __forceinline__ float bflo(unsigned u) { return __uint_as_float(u << 16); }
__device__ __forceinline__ float bfhi(unsigned u) { return __uint_as_float(u & 0xffff0000u); }

// ---------------- bucketed CSR build ----------------
__global__ __launch_bounds__(256)
void zero_bcnt_kernel(int* __restrict__ bcnt) {
    int t = threadIdx.x;
    if (t < NB) bcnt[t] = 0;
}

__global__ __launch_bounds__(256)
void bin_count_kernel(const int* __restrict__ edst, int* __restrict__ bcnt) {
    __shared__ int h[NB];
    int t = threadIdx.x;
    if (t < NB) h[t] = 0;
    __syncthreads();
    int e0 = blockIdx.x * EPB;
    for (int q = 0; q < EPB; q += 256) {
        int e = e0 + q + t;
        if (e < NE) atomicAdd(&h[edst[e] / NPB], 1);
    }
    __syncthreads();
    if (t < NB && h[t]) atomicAdd(&bcnt[t], h[t]);
}

__global__ __launch_bounds__(256)
void bin_scan_kernel(const int* __restrict__ bcnt, int* __restrict__ boff,
                     int* __restrict__ bcur) {
    __shared__ int s[NB];
    int t = threadIdx.x;
    if (t < NB) s[t] = bcnt[t];
    __syncthreads();
    if (t == 0) {
        int run = 0;
        for (int i = 0; i < NB; i++) { int c = s[i]; s[i] = run; run += c; }
        boff[NB] = run;   // == NE
    }
    __syncthreads();
    if (t < NB) { boff[t] = s[t]; bcur[t] = s[t]; }
}

// Each block claims a contiguous chunk per bucket, then writes packed records
// src | (dst_in_bucket << 17) into its exclusive chunk (dense, short window).
__global__ __launch_bounds__(256)
void bin_place_kernel(const int* __restrict__ esrc, const int* __restrict__ edst,
                      int* __restrict__ bcur, int* __restrict__ ebuf) {
    __shared__ int h[NB], base[NB], lcur[NB];
    int t = threadIdx.x;
    if (t < NB) h[t] = 0;
    __syncthreads();
    int e0 = blockIdx.x * EPB;
    for (int q = 0; q < EPB; q += 256) {
        int e = e0 + q + t;
        if (e < NE) atomicAdd(&h[edst[e] / NPB], 1);
    }
    __syncthreads();
    if (t < NB) {
        int c = h[t];
        base[t] = c ? atomicAdd(&bcur[t], c) : 0;
        lcur[t] = 0;
    }
    __syncthreads();
    for (int q = 0; q < EPB; q += 256) {
        int e = e0 + q + t;
        if (e < NE) {
            int d = edst[e], s = esrc[e];
            int b = d / NPB;
            int r = atomicAdd(&lcur[b], 1);
            ebuf[base[b] + r] = s | ((d - b * NPB) << 17);
        }
    }
}

// One block per bucket: per-node degree via LDS histogram.
__global__ __launch_bounds__(256)
void bucket_deg_kernel(const int* __restrict__ boff, const int* __restrict__ ebuf,
                       int* __restrict__ deg) {
    __shared__ int h[NPB];
    int b = blockIdx.x, t = threadIdx.x;
    for (int i = t; i < NPB; i += 256) h[i] = 0;
    __syncthreads();
    int jb = boff[b], je = boff[b + 1];
    for (int j = jb + t; j < je; j += 256) atomicAdd(&h[ebuf[j] >> 17], 1);
    __syncthreads();
    int n0 = b * NPB;
    for (int i = t; i < NPB; i += 256) {
        int n = n0 + i;
        if (n < NN) deg[n] = h[i] + 1;   // +1 self loop
    }
}

// One block per bucket: replay records with LDS cursors; sorted_src writes
// land in this block's exclusive CSR range (L2-local, written back once).
__global__ __launch_bounds__(256)
void bucket_scatter_kernel(const int* __restrict__ boff, const int* __restrict__ ebuf,
                           const int* __restrict__ off, int* __restrict__ sorted_src) {
    __shared__ int lcur[NPB];
    int b = blockIdx.x, t = threadIdx.x;
    int n0 = b * NPB;
    for (int i = t; i < NPB; i += 256) {
        int n = n0 + i;
        lcur[i] = (n < NN) ? off[n] + 1 : 0;   // +1: self loop occupies slot 0
    }
    __syncthreads();
    int jb = boff[b], je = boff[b + 1];
    for (int j = jb + t; j < je; j += 256) {
        int rec = ebuf[j];
        int p = atomicAdd(&lcur[rec >> 17], 1);
        sorted_src[p] = rec & 0x1FFFF;
    }
}

// ---------------- node-offset scan ----------------
__global__ __launch_bounds__(256)
void scan_block_kernel(const int* __restrict__ deg, int* __restrict__ off,
                       int* __restrict__ bsum) {
    __shared__ int s[256];
    int t = threadIdx.x, b = blockIdx.x, i = b * 256 + t;
    int v = (i < NN) ? deg[i] : 0;
    s[t] = v; __syncthreads();
#pragma unroll
    for (int o = 1; o < 256; o <<= 1) {
        int x = (t >= o) ? s[t - o] : 0;
        __syncthreads();
        s[t] += x;
        __syncthreads();
    }
    if (i < NN) off[i] = s[t] - v;
    if (t == 255) bsum[b] = s[255];
}

__global__ __launch_bounds__(256)
void scan_bsum_kernel(const int* __restrict__ bsum, int* __restrict__ bscan, int nb) {
    __shared__ int s[256];
    int t = threadIdx.x;
    int carry = 0;
    int nc = (nb + 255) / 256;
    for (int c = 0; c < nc; c++) {
        int i = c * 256 + t;
        int v = (i < nb) ? bsum[i] : 0;
        s[t] = v; __syncthreads();
#pragma unroll
        for (int o = 1; o < 256; o <<= 1) {
            int x = (t >= o) ? s[t - o] : 0;
            __syncthreads();
            s[t] += x;
            __syncthreads();
        }
        if (i < nb) bscan[i] = carry + s[t] - v;
        carry += s[255];
        __syncthreads();
    }
}

__global__ __launch_bounds__(256)
void place_kernel(int* __restrict__ off, const int* __restrict__ bscan,
                  int* __restrict__ sorted_src) {
    int i = blockIdx.x * 256 + threadIdx.x;
    if (i == 0) off[NN] = NT;
    if (i < NN) {
        int o = off[i] + bscan[i >> 8];
        off[i] = o;
        sorted_src[o] = i;   // self loop first
    }
}

// ---------------- fold weight blocks ----------------
__global__ __launch_bounds__(256)
void fold_B12_kernel(const float* __restrict__ W, const float* __restrict__ lw,
                     const float* __restrict__ as_, const float* __restrict__ ad_,
                     float* __restrict__ B, int F) {
    int t = blockIdx.x * 256 + threadIdx.x;
    if (t >= F * 88) return;
    int f = t / 88, j = t - f * 88;
    float v = 0.f;
    if (j < 40) v = W[f * 40 + j];
    else if (j < 80) v = lw[f * 40 + (j - 40)];
    else if (j < 84) {
        int h = j - 80; float s = 0.f;
        for (int d = 0; d < 10; d++) s += W[f * 40 + h * 10 + d] * as_[h * 10 + d];
        v = s;
    } else {
        int h = j - 84; float s = 0.f;
        for (int d = 0; d < 10; d++) s += W[f * 40 + h * 10 + d] * ad_[h * 10 + d];
        v = s;
    }
    B[t] = v;
}

__global__ __launch_bounds__(256)
void fold_B3_kernel(const float* __restrict__ W3, const float* __restrict__ as3,
                    const float* __restrict__ ad3, float* __restrict__ B) {
    int t = blockIdx.x * 256 + threadIdx.x;
    if (t >= 40 * 12) return;
    int f = t / 12, k = t - f * 12;
    float s = 0.f;
    if (k < 6) {
        int h = k;
        for (int c = 0; c < COUT; c++) s += W3[f * 726 + h * COUT + c] * as3[h * COUT + c];
    } else {
        int h = k - 6;
        for (int c = 0; c < COUT; c++) s += W3[f * 726 + h * COUT + c] * ad3[h * COUT + c];
    }
    B[t] = s;
}

// Fold W3/lw3 into bf16 MFMA B-fragment order.
__global__ __launch_bounds__(256)
void fold_Bf_kernel(const float* __restrict__ W3, const float* __restrict__ lw3,
                    __hip_bfloat16* __restrict__ Bf) {
    int t = blockIdx.x * 256 + threadIdx.x;
    if (t >= 9 * 8 * 64 * 8) return;
    int j = t & 7, lane = (t >> 3) & 63, ct = (t >> 9) & 7, kt = t >> 12;
    int k = kt * 32 + (lane >> 4) * 8 + j;
    int c = ct * 16 + (lane & 15);
    float v = 0.f;
    if (c < COUT) {
        if (k < 240) {
            int h = k / 40, f = k - h * 40;
            v = W3[f * 726 + h * COUT + c];
        } else if (k < 280) {
            int f = k - 240;
            v = lw3[f * COUT + c];
        }
    }
    Bf[t] = __float2bfloat16(v);
}

// ---------------- fused feature GEMM for layers 1/2 ----------------
// Gather tables: f<32 -> xbA (64B aligned bf16 rows); f in [32,40) + asrc
// scores -> combined xcB[node][16] bf16 (32B rows): [0:8]=feats, [8:12]=
// scores bf16. adst/agg stay fp32. fp32 asrc array no longer written.
template <int F>
__global__ __launch_bounds__(256)
void feature12_kernel(const float* __restrict__ A, const float* __restrict__ B,
                      const float* __restrict__ bias, const float* __restrict__ lbias,
                      __hip_bfloat16* __restrict__ xbA, __hip_bfloat16* __restrict__ xcB,
                      float* __restrict__ agg, float* __restrict__ adst) {
    __shared__ float sB[F * 88];
    const int t = threadIdx.x;
    for (int i = t; i < F * 88; i += 256) sB[i] = B[i];

    const int lane = t & 63;
    const int p = __builtin_amdgcn_readfirstlane(t >> 6);
    const int r = blockIdx.x * 64 + lane;
    const bool valid = r < NN;
    const int rr = valid ? r : NN - 1;

    float a[F];
    if (F % 4 == 0) {
        const float4* A4 = reinterpret_cast<const float4*>(A + (size_t)rr * F);
#pragma unroll
        for (int q = 0; q < F / 4; q++) {
            float4 v = A4[q];
            a[4 * q] = v.x; a[4 * q + 1] = v.y; a[4 * q + 2] = v.z; a[4 * q + 3] = v.w;
        }
    } else {
        const float2* A2 = reinterpret_cast<const float2*>(A + (size_t)rr * F);
#pragma unroll
        for (int q = 0; q < F / 2; q++) {
            float2 v = A2[q];
            a[2 * q] = v.x; a[2 * q + 1] = v.y;
        }
        if (F & 1) a[F - 1] = A[(size_t)rr * F + F - 1];
    }
    __syncthreads();

    for (int g = p; g < 11; g += 4) {
        const int j0 = g * 8;
        float acc[8];
#pragma unroll
        for (int k = 0; k < 8; k++) acc[k] = 0.f;
#pragma unroll
        for (int f = 0; f < F; f++) {
            float av = a[f];
            float4 b0 = *reinterpret_cast<const float4*>(&sB[f * 88 + j0]);
            float4 b1 = *reinterpret_cast<const float4*>(&sB[f * 88 + j0 + 4]);
            acc[0] += av * b0.x; acc[1] += av * b0.y;
            acc[2] += av * b0.z; acc[3] += av * b0.w;
            acc[4] += av * b1.x; acc[5] += av * b1.y;
            acc[6] += av * b1.z; acc[7] += av * b1.w;
        }
        if (!valid) continue;
        if (j0 < 32) {
            uint4 v;
            v.x = pkbf(acc[0], acc[1]); v.y = pkbf(acc[2], acc[3]);
            v.z = pkbf(acc[4], acc[5]); v.w = pkbf(acc[6], acc[7]);
            *reinterpret_cast<uint4*>(&xbA[(size_t)r * 32 + j0]) = v;
        } else if (j0 < 40) {   // j0 == 32: tail features -> xcB[0:8]
            uint4 v;
            v.x = pkbf(acc[0], acc[1]); v.y = pkbf(acc[2], acc[3]);
            v.z = pkbf(acc[4], acc[5]); v.w = pkbf(acc[6], acc[7]);
            *reinterpret_cast<uint4*>(&xcB[(size_t)r * 16]) = v;
        } else if (j0 < 80) {
            int j = j0 - 40;
#pragma unroll
            for (int k = 0; k < 8; k++) acc[k] += bias[j + k] + lbias[j + k];
            *reinterpret_cast<float4*>(agg + (size_t)r * 40 + j) =
                make_float4(acc[0], acc[1], acc[2], acc[3]);
            *reinterpret_cast<float4*>(agg + (size_t)r * 40 + j + 4) =
                make_float4(acc[4], acc[5], acc[6], acc[7]);
        } else {                // j0 == 80: scores -> xcB[8:12] bf16; adst fp32
            uint2 sv;
            sv.x = pkbf(acc[0], acc[1]); sv.y = pkbf(acc[2], acc[3]);
            *reinterpret_cast<uint2*>(&xcB[(size_t)r * 16 + 8]) = sv;
            *reinterpret_cast<float4*>(adst + (size_t)r * 8) =
                make_float4(acc[4], acc[5], acc[6], acc[7]);
        }
    }
}

// ---------------- layer 3 scores + bf16 h2 copies (zb + hpA + combined hcB) -
__global__ __launch_bounds__(256)
void feature3_kernel(const float* __restrict__ A, const float* __restrict__ B,
                     float* __restrict__ adst, __hip_bfloat16* __restrict__ zb,
                     __hip_bfloat16* __restrict__ hpA, __hip_bfloat16* __restrict__ hcB) {
    int r = blockIdx.x * 256 + threadIdx.x;
    if (r >= NN) return;
    float a[40];
    const float4* A4 = reinterpret_cast<const float4*>(A + (size_t)r * 40);
#pragma unroll
    for (int q = 0; q < 10; q++) {
        float4 v = A4[q];
        a[4 * q] = v.x; a[4 * q + 1] = v.y; a[4 * q + 2] = v.z; a[4 * q + 3] = v.w;
    }
    __hip_bfloat16* zr = zb + (size_t)r * 288 + 240;
    __hip_bfloat16* ha = hpA + (size_t)r * 32;
    __hip_bfloat16* hb = hcB + (size_t)r * 16;
#pragma unroll
    for (int f = 0; f < 40; f++) {
        __hip_bfloat16 v = __float2bfloat16(a[f]);
        zr[f] = v;
        if (f < 32) ha[f] = v; else hb[f - 32] = v;
    }
#pragma unroll
    for (int f = 40; f < 48; f++) zr[f] = __float2bfloat16(0.f);

    float acc[12];
#pragma unroll
    for (int k = 0; k < 12; k++) acc[k] = 0.f;
#pragma unroll
    for (int f = 0; f < 40; f++) {
        float av = a[f];
#pragma unroll
        for (int k = 0; k < 12; k++) acc[k] += av * B[f * 12 + k];
    }
    uint4 sv;
    sv.x = pkbf(acc[0], acc[1]); sv.y = pkbf(acc[2], acc[3]);
    sv.z = pkbf(acc[4], acc[5]); sv.w = 0u;
    *reinterpret_cast<uint4*>(&hcB[(size_t)r * 16 + 8]) = sv;   // scores [8:14]
    *reinterpret_cast<float4*>(adst + (size_t)r * 8) = make_float4(acc[6], acc[7], acc[8], acc[9]);
    *reinterpret_cast<float2*>(adst + (size_t)r * 8 + 4) = make_float2(acc[10], acc[11]);
}

// ---------------- CSR aggregation, H=4, fused weights (LDS), fused ELU ------
// Round-10 structure, 2 lines/edge: xbA (64B row) + xcB (32B row: tail feats
// AND scores in the same line).
__global__ __launch_bounds__(256)
void agg4_csr_kernel(const int* __restrict__ off, const int* __restrict__ srt,
                     const float* __restrict__ adst,
                     const __hip_bfloat16* __restrict__ xbA,
                     const __hip_bfloat16* __restrict__ xcB, float* agg) {
    __shared__ float sW[4][64 * 4];
    __shared__ int   sS[4][64];
    int t = threadIdx.x;
    int wslot = t >> 6;
    int wid = (blockIdx.x * 256 + t) >> 6;
    int d = __builtin_amdgcn_readfirstlane(wid);
    if (d >= NN) return;
    int lane = t & 63;
    bool act = lane < 40;
    int f = act ? lane : 0;
    int hh = f / 10;
    const __hip_bfloat16* xt = (f < 32) ? xbA : xcB;
    const int sh = (f < 32) ? 5 : 4;
    const int fo = (f < 32) ? f : (f - 32);
    float4 bv = *reinterpret_cast<const float4*>(adst + (size_t)d * 8);
    int jb = off[d], je = off[d + 1];
    float acc = 0.f, ds = 0.f;
    for (int c0 = jb; c0 < je; c0 += 64) {
        int cnt = je - c0; if (cnt > 64) cnt = 64;
        if (lane < cnt) {   // phase A: one lane per edge; bf16 scores
            int s = srt[c0 + lane];
            sS[wslot][lane] = s;
            uint2 sv = *reinterpret_cast<const uint2*>(&xcB[(size_t)s * 16 + 8]);
            float4 w;
            w.x = __expf(lrelu(bflo(sv.x) + bv.x));
            w.y = __expf(lrelu(bfhi(sv.x) + bv.y));
            w.z = __expf(lrelu(bflo(sv.y) + bv.z));
            w.w = __expf(lrelu(bfhi(sv.y) + bv.w));
            *reinterpret_cast<float4*>(&sW[wslot][lane * 4]) = w;
        }
        int j = 0;          // phase B: FMA loop (round-10 order)
        for (; j + 3 < cnt; j += 4) {
            int s0 = sS[wslot][j], s1 = sS[wslot][j + 1];
            int s2 = sS[wslot][j + 2], s3 = sS[wslot][j + 3];
            float w0 = sW[wslot][(j + 0) * 4 + hh];
            float w1 = sW[wslot][(j + 1) * 4 + hh];
            float w2 = sW[wslot][(j + 2) * 4 + hh];
            float w3 = sW[wslot][(j + 3) * 4 + hh];
            float x0 = __bfloat162float(xt[((size_t)s0 << sh) + fo]);
            float x1 = __bfloat162float(xt[((size_t)s1 << sh) + fo]);
            float x2 = __bfloat162float(xt[((size_t)s2 << sh) + fo]);
            float x3 = __bfloat162float(xt[((size_t)s3 << sh) + fo]);
            acc += w0 * x0; acc += w1 * x1; acc += w2 * x2; acc += w3 * x3;
            ds += (w0 + w1) + (w2 + w3);
        }
        for (; j < cnt; ++j) {
            int s = sS[wslot][j];
            float w = sW[wslot][j * 4 + hh];
            acc += w * __bfloat162float(xt[((size_t)s << sh) + fo]);
            ds += w;
        }
    }
    if (act) {
        float v = agg[(size_t)d * 40 + f] + acc / ds;
        agg[(size_t)d * 40 + f] = elu1(v);   // ELU fused (layers 1/2 only)
    }
}

// ---------------- CSR aggregation, H=6 -> bf16 z, fused weights (LDS) -------
// Round-10 structure, 2 lines/edge: hpA (64B row) + hcB (32B row with tail
// feats + 6 bf16 scores).
__global__ __launch_bounds__(256)
void z6_csr_kernel(const int* __restrict__ off, const int* __restrict__ srt,
                   const float* __restrict__ adst,
                   const __hip_bfloat16* __restrict__ hpA,
                   const __hip_bfloat16* __restrict__ hcB, __hip_bfloat16* zb) {
    __shared__ float sW[4][64 * 6];
    __shared__ int   sS[4][64];
    int t = threadIdx.x;
    int wslot = t >> 6;
    int wid = (blockIdx.x * 256 + t) >> 6;
    int d = __builtin_amdgcn_readfirstlane(wid);
    if (d >= NN) return;
    int lane = t & 63;
    bool act = lane < 40;
    int f = act ? lane : 0;
    const __hip_bfloat16* ht = (f < 32) ? hpA : hcB;
    const int sh = (f < 32) ? 5 : 4;
    const int fo = (f < 32) ? f : (f - 32);
    float4 bv0 = *reinterpret_cast<const float4*>(adst + (size_t)d * 8);
    float2 bv1 = *reinterpret_cast<const float2*>(adst + (size_t)d * 8 + 4);
    int jb = off[d], je = off[d + 1];
    float acc[6], ds[6];
#pragma unroll
    for (int h = 0; h < 6; h++) { acc[h] = 0.f; ds[h] = 0.f; }
    for (int c0 = jb; c0 < je; c0 += 64) {
        int cnt = je - c0; if (cnt > 64) cnt = 64;
        if (lane < cnt) {   // phase A: bf16 scores from the combined row
            int s = srt[c0 + lane];
            sS[wslot][lane] = s;
            uint4 sv = *reinterpret_cast<const uint4*>(&hcB[(size_t)s * 16 + 8]);
            float* wp = &sW[wslot][lane * 6];
            *reinterpret_cast<float4*>(wp) = make_float4(
                __expf(lrelu(bflo(sv.x) + bv0.x)), __expf(lrelu(bfhi(sv.x) + bv0.y)),
                __expf(lrelu(bflo(sv.y) + bv0.z)), __expf(lrelu(bfhi(sv.y) + bv0.w)));
            *reinterpret_cast<float2*>(wp + 4) = make_float2(
                __expf(lrelu(bflo(sv.z) + bv1.x)), __expf(lrelu(bfhi(sv.z) + bv1.y)));
        }
        int j = 0;          // phase B (round-10 pairing)
        for (; j + 1 < cnt; j += 2) {
            int s0 = sS[wslot][j], s1 = sS[wslot][j + 1];
            float hv0 = __bfloat162float(ht[((size_t)s0 << sh) + fo]);
            float hv1 = __bfloat162float(ht[((size_t)s1 << sh) + fo]);
            const float* wp = &sW[wslot][j * 6];
#pragma unroll
            for (int h = 0; h < 6; h++) {
                float w0 = wp[h], w1 = wp[6 + h];
                acc[h] += w0 * hv0; acc[h] += w1 * hv1;
                ds[h] += w0 + w1;
            }
        }
        for (; j < cnt; ++j) {
            int s = sS[wslot][j];
            float hv = __bfloat162float(ht[((size_t)s << sh) + fo]);
            const float* wp = &sW[wslot][j * 6];
#pragma unroll
            for (int h = 0; h < 6; h++) {
                acc[h] += wp[h] * hv;
                ds[h] += wp[h];
            }
        }
    }
    if (act) {
#pragma unroll
        for (int h = 0; h < 6; h++)
            zb[(size_t)d * 288 + h * 40 + f] =
                __float2bfloat16(acc[h] / ds[h] * (1.0f / 6.0f));
    }
}

// ---------------- MFMA GEMM: out[100000x121] = A[100000x288]@B[288x128] + bias
__global__ __launch_bounds__(256)
void zgemm_mfma_kernel(const __hip_bfloat16* __restrict__ Ab,
                       const __hip_bfloat16* __restrict__ Bf,
                       const float* __restrict__ b3, const float* __restrict__ lb3,
                       float* __restrict__ out) {
    const int t = threadIdx.x;
    const int lane = t & 63, w = t >> 6;
    const int wr = w & 1, wc = w >> 1;
    const int n0 = blockIdx.x * 128;
    const short* As = (const short*)Ab;
    const short* Bs = (const short*)Bf;

    f32x4 acc[4][4];
#pragma unroll
    for (int i = 0; i < 4; i++)
#pragma unroll
        for (int j = 0; j < 4; j++) acc[i][j] = (f32x4){0.f, 0.f, 0.f, 0.f};

    const int arow = n0 + wr * 64 + (lane & 15);
    const int koff = (lane >> 4) * 8;

    for (int kk = 0; kk < 9; kk++) {
        bf16x8 af[4], bfr[4];
#pragma unroll
        for (int i = 0; i < 4; i++) {
            int r = arow + i * 16; if (r > NN - 1) r = NN - 1;
            af[i] = *(const bf16x8*)(As + (size_t)r * 288 + kk * 32 + koff);
        }
#pragma unroll
        for (int j = 0; j < 4; j++) {
            int ct = wc * 4 + j;
            bfr[j] = *(const bf16x8*)(Bs + (((size_t)kk * 8 + ct) * 64 + lane) * 8);
        }
#pragma unroll
        for (int i = 0; i < 4; i++)
#pragma unroll
            for (int j = 0; j < 4; j++)
                acc[i][j] = __builtin_amdgcn_mfma_f32_16x16x32_bf16(af[i], bfr[j], acc[i][j], 0, 0, 0);
    }

    const int c_base = wc * 64 + (lane & 15);
    const int r_quad = (lane >> 4) * 4;
#pragma unroll
    for (int j = 0; j < 4; j++) {
        int c = c_base + j * 16;
        if (c >= COUT) continue;
        float bias = b3[c] + lb3[c];
#pragma unroll
        for (int i = 0; i < 4; i++) {
            int nb = n0 + wr * 64 + i * 16 + r_quad;
#pragma unroll
            for (int q = 0; q < 4; q++) {
                int n = nb + q;
                if (n < NN) out[(size_t)n * COUT + c] = acc[i][j][q] + bias;
            }
        }
    }
}

extern "C" void kernel_launch(void* const* d_in, const int* in_sizes, int n_in,
                              void* d_out, int out_size, void* d_ws, size_t ws_size,
                              hipStream_t stream) {
    const float* x   = (const float*)d_in[0];
    const int*   ei  = (const int*)d_in[1];
    const float* W1  = (const float*)d_in[2];
    const float* as1 = (const float*)d_in[3];
    const float* ad1 = (const float*)d_in[4];
    const float* b1  = (const float*)d_in[5];
    const float* lw1 = (const float*)d_in[6];
    const float* lb1 = (const float*)d_in[7];
    const float* W2  = (const float*)d_in[8];
    const float* as2 = (const float*)d_in[9];
    const float* ad2 = (const float*)d_in[10];
    const float* b2  = (const float*)d_in[11];
    const float* lw2 = (const float*)d_in[12];
    const float* lb2 = (const float*)d_in[13];
    const float* W3  = (const float*)d_in[14];
    const float* as3 = (const float*)d_in[15];
    const float* ad3 = (const float*)d_in[16];
    const float* b3  = (const float*)d_in[17];
    const float* lw3 = (const float*)d_in[18];
    const float* lb3 = (const float*)d_in[19];
    float* out = (float*)d_out;
    float* ws  = (float*)d_ws;

    const int* esrc = ei;
    const int* edst = ei + NE;

    // ---- workspace layout (floats unless noted) ----
    // [0, 1.6M)      xbA (bf16) | hpA (bf16, layer 3) - same slot
    // [1.6M, 2.4M)   xcB (bf16, 100000x16) | hcB      - same slot
    // [4M, 8M)       agg
    // [8.8M, 9.6M)   adst ; [9.6M,...) Bc, Bf
    // [9.628M, 24.028M) zb (bf16)
    // [24.028M, ...) CSR ints
    __hip_bfloat16* xbA = (__hip_bfloat16*)ws;
    __hip_bfloat16* xcB = (__hip_bfloat16*)(ws + 1600000);
    float* agg  = ws + 4000000;
    float* adst = ws + 8800000;
    float* Bc   = ws + 9600000;
    __hip_bfloat16* Bf = (__hip_bfloat16*)(ws + 9608000);
    __hip_bfloat16* zb = (__hip_bfloat16*)(ws + 9628000);
    __hip_bfloat16* hpA = xbA;   // layer 3 reuses the same slots
    __hip_bfloat16* hcB = xcB;
    int* ib     = (int*)(ws + 24028000);
    int* deg    = ib;                 // 100,352
    int* off    = ib + 100352;        // 100,001 (+pad)
    int* bcnt   = ib + 200704;        // 128
    int* boff   = ib + 200832;        // 129
    int* bcur   = ib + 200992;        // 128
    int* bsum   = ib + 300704;        // 512
    int* bscan  = ib + 301216;        // 512
    int* sorted = ib + 301728;        // 1,700,000 -> ends 2,001,728
    int* ebuf   = ib + 2001728;       // 1,600,000 -> ends 3,601,728

    const int nodeBlocks = (NN + 255) / 256;       // 391
    const int binBlocks  = (NE + EPB - 1) / EPB;   // 196
    const int waveBlocks = NN / 4;                 // 25000
    const int featBlocks = (NN + 63) / 64;         // 1563 (64 rows/block)

    // ---- bucketed CSR build ----
    zero_bcnt_kernel<<<1, 256, 0, stream>>>(bcnt);
    bin_count_kernel<<<binBlocks, 256, 0, stream>>>(edst, bcnt);
    bin_scan_kernel<<<1, 256, 0, stream>>>(bcnt, boff, bcur);
    bin_place_kernel<<<binBlocks, 256, 0, stream>>>(esrc, edst, bcur, ebuf);
    bucket_deg_kernel<<<NB, 256, 0, stream>>>(boff, ebuf, deg);
    scan_block_kernel<<<nodeBlocks, 256, 0, stream>>>(deg, off, bsum);
    scan_bsum_kernel<<<1, 256, 0, stream>>>(bsum, bscan, nodeBlocks);
    place_kernel<<<nodeBlocks, 256, 0, stream>>>(off, bscan, sorted);
    bucket_scatter_kernel<<<NB, 256, 0, stream>>>(boff, ebuf, off, sorted);

    // ---- layer 1 ----
    fold_B12_kernel<<<(FIN * 88 + 255) / 256, 256, 0, stream>>>(W1, lw1, as1, ad1, Bc, FIN);
    feature12_kernel<FIN><<<featBlocks, 256, 0, stream>>>(x, Bc, b1, lb1, xbA, xcB, agg, adst);
    agg4_csr_kernel<<<waveBlocks, 256, 0, stream>>>(off, sorted, adst, xbA, xcB, agg);

    // ---- layer 2 ----
    fold_B12_kernel<<<(HID * 88 + 255) / 256, 256, 0, stream>>>(W2, lw2, as2, ad2, Bc, HID);
    feature12_kernel<HID><<<featBlocks, 256, 0, stream>>>(agg, Bc, b2, lb2, xbA, xcB, agg, adst);
    agg4_csr_kernel<<<waveBlocks, 256, 0, stream>>>(off, sorted, adst, xbA, xcB, agg);

    // ---- layer 3 ----
    fold_B3_kernel<<<(40 * 12 + 255) / 256, 256, 0, stream>>>(W3, as3, ad3, Bc);
    fold_Bf_kernel<<<(9 * 8 * 64 * 8 + 255) / 256, 256, 0, stream>>>(W3, lw3, Bf);
    feature3_kernel<<<nodeBlocks, 256, 0, stream>>>(agg, Bc, adst, zb, hpA, hcB);
    z6_csr_kernel<<<waveBlocks, 256, 0, stream>>>(off, sorted, adst, hpA, hcB, zb);
    zgemm_mfma_kernel<<<(NN + 127) / 128, 256, 0, stream>>>(zb, Bf, b3, lb3, out);
}

// Round 12
// 511.332 us; speedup vs baseline: 1.1991x; 1.0116x over previous
//
#include <hip/hip_runtime.h>
#include <hip/hip_bf16.h>
#include <math.h>

// GAT x3 on N=100000 nodes, E=1600000 edges (+ self loops).
// Round 17: z6 phase-B MLP. Evidence across r11-r16: VALU-shaving didn't
// move z6, traffic-shaving (-30% FETCH) moved it only -2.5us -> it's
// LATENCY-bound: deg/2 sequential rounds x 2 outstanding gathers. agg4
// (already 4 gathers/round) is faster per edge. Change: z6 phase B 4-edge
// unroll (4 hp gathers in flight), NOTHING else (r13's 8-deep failed via
// VGPR 44 + nt-store write amplification; staying at 4 keeps VGPR ~30).
// Per-h accumulation order preserved edge-sequentially.
// (R16: scores in featB line, 2 lines/edge; R15: bf16 gather tables;
// R14: split aligned tables; R10: fused weights in LDS; R9: feature12
// LDS-B; R8: bucketed CSR build.)

#define NN 100000
#define NE 1600000
#define NT (NE + NN)
#define FIN 50
#define HID 40
#define COUT 121

#define NB 128           // buckets
#define NPB 782          // nodes per bucket (128*782 = 100096 >= NN)
#define EPB 8192         // edges per bin block

typedef __attribute__((ext_vector_type(8))) short bf16x8;
typedef __attribute__((ext_vector_type(4))) float f32x4;

__device__ __forceinline__ float lrelu(float x) { return fmaxf(x, 0.2f * x); }
__device__ __forceinline__ float elu1(float x)  { return x > 0.f ? x : __expf(x) - 1.f; }
__device__ __forceinline__ unsigned pkbf(float a, float b) {
    __hip_bfloat16 ha = __float2bfloat16(a), hb = __float2bfloat16(b);
    return ((unsigned)*reinterpret_cast<unsigned short*>(&hb) << 16) |
           *reinterpret_cast<unsigned short*>(&ha);
}
__device__ __forceinline__ float bflo(unsigned u) { return __uint_as_float(u << 16); }
__device__ __forceinline__ float bfhi(unsigned u) { return __uint_as_float(u & 0xffff0000u); }

// ---------------- bucketed CSR build ----------------
__global__ __launch_bounds__(256)
void zero_bcnt_kernel(int* __restrict__ bcnt) {
    int t = threadIdx.x;
    if (t < NB) bcnt[t] = 0;
}

__global__ __launch_bounds__(256)
void bin_count_kernel(const int* __restrict__ edst, int* __restrict__ bcnt) {
    __shared__ int h[NB];
    int t = threadIdx.x;
    if (t < NB) h[t] = 0;
    __syncthreads();
    int e0 = blockIdx.x * EPB;
    for (int q = 0; q < EPB; q += 256) {
        int e = e0 + q + t;
        if (e < NE) atomicAdd(&h[edst[e] / NPB], 1);
    }
    __syncthreads();
    if (t < NB && h[t]) atomicAdd(&bcnt[t], h[t]);
}

__global__ __launch_bounds__(256)
void bin_scan_kernel(const int* __restrict__ bcnt, int* __restrict__ boff,
                     int* __restrict__ bcur) {
    __shared__ int s[NB];
    int t = threadIdx.x;
    if (t < NB) s[t] = bcnt[t];
    __syncthreads();
    if (t == 0) {
        int run = 0;
        for (int i = 0; i < NB; i++) { int c = s[i]; s[i] = run; run += c; }
        boff[NB] = run;   // == NE
    }
    __syncthreads();
    if (t < NB) { boff[t] = s[t]; bcur[t] = s[t]; }
}

// Each block claims a contiguous chunk per bucket, then writes packed records
// src | (dst_in_bucket << 17) into its exclusive chunk (dense, short window).
__global__ __launch_bounds__(256)
void bin_place_kernel(const int* __restrict__ esrc, const int* __restrict__ edst,
                      int* __restrict__ bcur, int* __restrict__ ebuf) {
    __shared__ int h[NB], base[NB], lcur[NB];
    int t = threadIdx.x;
    if (t < NB) h[t] = 0;
    __syncthreads();
    int e0 = blockIdx.x * EPB;
    for (int q = 0; q < EPB; q += 256) {
        int e = e0 + q + t;
        if (e < NE) atomicAdd(&h[edst[e] / NPB], 1);
    }
    __syncthreads();
    if (t < NB) {
        int c = h[t];
        base[t] = c ? atomicAdd(&bcur[t], c) : 0;
        lcur[t] = 0;
    }
    __syncthreads();
    for (int q = 0; q < EPB; q += 256) {
        int e = e0 + q + t;
        if (e < NE) {
            int d = edst[e], s = esrc[e];
            int b = d / NPB;
            int r = atomicAdd(&lcur[b], 1);
            ebuf[base[b] + r] = s | ((d - b * NPB) << 17);
        }
    }
}

// One block per bucket: per-node degree via LDS histogram.
__global__ __launch_bounds__(256)
void bucket_deg_kernel(const int* __restrict__ boff, const int* __restrict__ ebuf,
                       int* __restrict__ deg) {
    __shared__ int h[NPB];
    int b = blockIdx.x, t = threadIdx.x;
    for (int i = t; i < NPB; i += 256) h[i] = 0;
    __syncthreads();
    int jb = boff[b], je = boff[b + 1];
    for (int j = jb + t; j < je; j += 256) atomicAdd(&h[ebuf[j] >> 17], 1);
    __syncthreads();
    int n0 = b * NPB;
    for (int i = t; i < NPB; i += 256) {
        int n = n0 + i;
        if (n < NN) deg[n] = h[i] + 1;   // +1 self loop
    }
}

// One block per bucket: replay records with LDS cursors; sorted_src writes
// land in this block's exclusive CSR range (L2-local, written back once).
__global__ __launch_bounds__(256)
void bucket_scatter_kernel(const int* __restrict__ boff, const int* __restrict__ ebuf,
                           const int* __restrict__ off, int* __restrict__ sorted_src) {
    __shared__ int lcur[NPB];
    int b = blockIdx.x, t = threadIdx.x;
    int n0 = b * NPB;
    for (int i = t; i < NPB; i += 256) {
        int n = n0 + i;
        lcur[i] = (n < NN) ? off[n] + 1 : 0;   // +1: self loop occupies slot 0
    }
    __syncthreads();
    int jb = boff[b], je = boff[b + 1];
    for (int j = jb + t; j < je; j += 256) {
        int rec = ebuf[j];
        int p = atomicAdd(&lcur[rec >> 17], 1);
        sorted_src[p] = rec & 0x1FFFF;
    }
}

// ---------------- node-offset scan ----------------
__global__ __launch_bounds__(256)
void scan_block_kernel(const int* __restrict__ deg, int* __restrict__ off,
                       int* __restrict__ bsum) {
    __shared__ int s[256];
    int t = threadIdx.x, b = blockIdx.x, i = b * 256 + t;
    int v = (i < NN) ? deg[i] : 0;
    s[t] = v; __syncthreads();
#pragma unroll
    for (int o = 1; o < 256; o <<= 1) {
        int x = (t >= o) ? s[t - o] : 0;
        __syncthreads();
        s[t] += x;
        __syncthreads();
    }
    if (i < NN) off[i] = s[t] - v;
    if (t == 255) bsum[b] = s[255];
}

__global__ __launch_bounds__(256)
void scan_bsum_kernel(const int* __restrict__ bsum, int* __restrict__ bscan, int nb) {
    __shared__ int s[256];
    int t = threadIdx.x;
    int carry = 0;
    int nc = (nb + 255) / 256;
    for (int c = 0; c < nc; c++) {
        int i = c * 256 + t;
        int v = (i < nb) ? bsum[i] : 0;
        s[t] = v; __syncthreads();
#pragma unroll
        for (int o = 1; o < 256; o <<= 1) {
            int x = (t >= o) ? s[t - o] : 0;
            __syncthreads();
            s[t] += x;
            __syncthreads();
        }
        if (i < nb) bscan[i] = carry + s[t] - v;
        carry += s[255];
        __syncthreads();
    }
}

__global__ __launch_bounds__(256)
void place_kernel(int* __restrict__ off, const int* __restrict__ bscan,
                  int* __restrict__ sorted_src) {
    int i = blockIdx.x * 256 + threadIdx.x;
    if (i == 0) off[NN] = NT;
    if (i < NN) {
        int o = off[i] + bscan[i >> 8];
        off[i] = o;
        sorted_src[o] = i;   // self loop first
    }
}

// ---------------- fold weight blocks ----------------
__global__ __launch_bounds__(256)
void fold_B12_kernel(const float* __restrict__ W, const float* __restrict__ lw,
                     const float* __restrict__ as_, const float* __restrict__ ad_,
                     float* __restrict__ B, int F) {
    int t = blockIdx.x * 256 + threadIdx.x;
    if (t >= F * 88) return;
    int f = t / 88, j = t - f * 88;
    float v = 0.f;
    if (j < 40) v = W[f * 40 + j];
    else if (j < 80) v = lw[f * 40 + (j - 40)];
    else if (j < 84) {
        int h = j - 80; float s = 0.f;
        for (int d = 0; d < 10; d++) s += W[f * 40 + h * 10 + d] * as_[h * 10 + d];
        v = s;
    } else {
        int h = j - 84; float s = 0.f;
        for (int d = 0; d < 10; d++) s += W[f * 40 + h * 10 + d] * ad_[h * 10 + d];
        v = s;
    }
    B[t] = v;
}

__global__ __launch_bounds__(256)
void fold_B3_kernel(const float* __restrict__ W3, const float* __restrict__ as3,
                    const float* __restrict__ ad3, float* __restrict__ B) {
    int t = blockIdx.x * 256 + threadIdx.x;
    if (t >= 40 * 12) return;
    int f = t / 12, k = t - f * 12;
    float s = 0.f;
    if (k < 6) {
        int h = k;
        for (int c = 0; c < COUT; c++) s += W3[f * 726 + h * COUT + c] * as3[h * COUT + c];
    } else {
        int h = k - 6;
        for (int c = 0; c < COUT; c++) s += W3[f * 726 + h * COUT + c] * ad3[h * COUT + c];
    }
    B[t] = s;
}

// Fold W3/lw3 into bf16 MFMA B-fragment order.
__global__ __launch_bounds__(256)
void fold_Bf_kernel(const float* __restrict__ W3, const float* __restrict__ lw3,
                    __hip_bfloat16* __restrict__ Bf) {
    int t = blockIdx.x * 256 + threadIdx.x;
    if (t >= 9 * 8 * 64 * 8) return;
    int j = t & 7, lane = (t >> 3) & 63, ct = (t >> 9) & 7, kt = t >> 12;
    int k = kt * 32 + (lane >> 4) * 8 + j;
    int c = ct * 16 + (lane & 15);
    float v = 0.f;
    if (c < COUT) {
        if (k < 240) {
            int h = k / 40, f = k - h * 40;
            v = W3[f * 726 + h * COUT + c];
        } else if (k < 280) {
            int f = k - 240;
            v = lw3[f * COUT + c];
        }
    }
    Bf[t] = __float2bfloat16(v);
}

// ---------------- fused feature GEMM for layers 1/2 ----------------
// Gather tables: f<32 -> xbA (64B aligned bf16 rows); f in [32,40) + asrc
// scores -> combined xcB[node][16] bf16 (32B rows): [0:8]=feats, [8:12]=
// scores bf16. adst/agg stay fp32.
template <int F>
__global__ __launch_bounds__(256)
void feature12_kernel(const float* __restrict__ A, const float* __restrict__ B,
                      const float* __restrict__ bias, const float* __restrict__ lbias,
                      __hip_bfloat16* __restrict__ xbA, __hip_bfloat16* __restrict__ xcB,
                      float* __restrict__ agg, float* __restrict__ adst) {
    __shared__ float sB[F * 88];
    const int t = threadIdx.x;
    for (int i = t; i < F * 88; i += 256) sB[i] = B[i];

    const int lane = t & 63;
    const int p = __builtin_amdgcn_readfirstlane(t >> 6);
    const int r = blockIdx.x * 64 + lane;
    const bool valid = r < NN;
    const int rr = valid ? r : NN - 1;

    float a[F];
    if (F % 4 == 0) {
        const float4* A4 = reinterpret_cast<const float4*>(A + (size_t)rr * F);
#pragma unroll
        for (int q = 0; q < F / 4; q++) {
            float4 v = A4[q];
            a[4 * q] = v.x; a[4 * q + 1] = v.y; a[4 * q + 2] = v.z; a[4 * q + 3] = v.w;
        }
    } else {
        const float2* A2 = reinterpret_cast<const float2*>(A + (size_t)rr * F);
#pragma unroll
        for (int q = 0; q < F / 2; q++) {
            float2 v = A2[q];
            a[2 * q] = v.x; a[2 * q + 1] = v.y;
        }
        if (F & 1) a[F - 1] = A[(size_t)rr * F + F - 1];
    }
    __syncthreads();

    for (int g = p; g < 11; g += 4) {
        const int j0 = g * 8;
        float acc[8];
#pragma unroll
        for (int k = 0; k < 8; k++) acc[k] = 0.f;
#pragma unroll
        for (int f = 0; f < F; f++) {
            float av = a[f];
            float4 b0 = *reinterpret_cast<const float4*>(&sB[f * 88 + j0]);
            float4 b1 = *reinterpret_cast<const float4*>(&sB[f * 88 + j0 + 4]);
            acc[0] += av * b0.x; acc[1] += av * b0.y;
            acc[2] += av * b0.z; acc[3] += av * b0.w;
            acc[4] += av * b1.x; acc[5] += av * b1.y;
            acc[6] += av * b1.z; acc[7] += av * b1.w;
        }
        if (!valid) continue;
        if (j0 < 32) {
            uint4 v;
            v.x = pkbf(acc[0], acc[1]); v.y = pkbf(acc[2], acc[3]);
            v.z = pkbf(acc[4], acc[5]); v.w = pkbf(acc[6], acc[7]);
            *reinterpret_cast<uint4*>(&xbA[(size_t)r * 32 + j0]) = v;
        } else if (j0 < 40) {   // j0 == 32: tail features -> xcB[0:8]
            uint4 v;
            v.x = pkbf(acc[0], acc[1]); v.y = pkbf(acc[2], acc[3]);
            v.z = pkbf(acc[4], acc[5]); v.w = pkbf(acc[6], acc[7]);
            *reinterpret_cast<uint4*>(&xcB[(size_t)r * 16]) = v;
        } else if (j0 < 80) {
            int j = j0 - 40;
#pragma unroll
            for (int k = 0; k < 8; k++) acc[k] += bias[j + k] + lbias[j + k];
            *reinterpret_cast<float4*>(agg + (size_t)r * 40 + j) =
                make_float4(acc[0], acc[1], acc[2], acc[3]);
            *reinterpret_cast<float4*>(agg + (size_t)r * 40 + j + 4) =
                make_float4(acc[4], acc[5], acc[6], acc[7]);
        } else {                // j0 == 80: scores -> xcB[8:12] bf16; adst fp32
            uint2 sv;
            sv.x = pkbf(acc[0], acc[1]); sv.y = pkbf(acc[2], acc[3]);
            *reinterpret_cast<uint2*>(&xcB[(size_t)r * 16 + 8]) = sv;
            *reinterpret_cast<float4*>(adst + (size_t)r * 8) =
                make_float4(acc[4], acc[5], acc[6], acc[7]);
        }
    }
}

// ---------------- layer 3 scores + bf16 h2 copies (zb + hpA + combined hcB) -
__global__ __launch_bounds__(256)
void feature3_kernel(const float* __restrict__ A, const float* __restrict__ B,
                     float* __restrict__ adst, __hip_bfloat16* __restrict__ zb,
                     __hip_bfloat16* __restrict__ hpA, __hip_bfloat16* __restrict__ hcB) {
    int r = blockIdx.x * 256 + threadIdx.x;
    if (r >= NN) return;
    float a[40];
    const float4* A4 = reinterpret_cast<const float4*>(A + (size_t)r * 40);
#pragma unroll
    for (int q = 0; q < 10; q++) {
        float4 v = A4[q];
        a[4 * q] = v.x; a[4 * q + 1] = v.y; a[4 * q + 2] = v.z; a[4 * q + 3] = v.w;
    }
    __hip_bfloat16* zr = zb + (size_t)r * 288 + 240;
    __hip_bfloat16* ha = hpA + (size_t)r * 32;
    __hip_bfloat16* hb = hcB + (size_t)r * 16;
#pragma unroll
    for (int f = 0; f < 40; f++) {
        __hip_bfloat16 v = __float2bfloat16(a[f]);
        zr[f] = v;
        if (f < 32) ha[f] = v; else hb[f - 32] = v;
    }
#pragma unroll
    for (int f = 40; f < 48; f++) zr[f] = __float2bfloat16(0.f);

    float acc[12];
#pragma unroll
    for (int k = 0; k < 12; k++) acc[k] = 0.f;
#pragma unroll
    for (int f = 0; f < 40; f++) {
        float av = a[f];
#pragma unroll
        for (int k = 0; k < 12; k++) acc[k] += av * B[f * 12 + k];
    }
    uint4 sv;
    sv.x = pkbf(acc[0], acc[1]); sv.y = pkbf(acc[2], acc[3]);
    sv.z = pkbf(acc[4], acc[5]); sv.w = 0u;
    *reinterpret_cast<uint4*>(&hcB[(size_t)r * 16 + 8]) = sv;   // scores [8:14]
    *reinterpret_cast<float4*>(adst + (size_t)r * 8) = make_float4(acc[6], acc[7], acc[8], acc[9]);
    *reinterpret_cast<float2*>(adst + (size_t)r * 8 + 4) = make_float2(acc[10], acc[11]);
}

// ---------------- CSR aggregation, H=4, fused weights (LDS), fused ELU ------
// Round-10 structure, 2 lines/edge: xbA (64B row) + xcB (32B row: tail feats
// AND scores in the same line). 4 gathers/round.
__global__ __launch_bounds__(256)
void agg4_csr_kernel(const int* __restrict__ off, const int* __restrict__ srt,
                     const float* __restrict__ adst,
                     const __hip_bfloat16* __restrict__ xbA,
                     const __hip_bfloat16* __restrict__ xcB, float* agg) {
    __shared__ float sW[4][64 * 4];
    __shared__ int   sS[4][64];
    int t = threadIdx.x;
    int wslot = t >> 6;
    int wid = (blockIdx.x * 256 + t) >> 6;
    int d = __builtin_amdgcn_readfirstlane(wid);
    if (d >= NN) return;
    int lane = t & 63;
    bool act = lane < 40;
    int f = act ? lane : 0;
    int hh = f / 10;
    const __hip_bfloat16* xt = (f < 32) ? xbA : xcB;
    const int sh = (f < 32) ? 5 : 4;
    const int fo = (f < 32) ? f : (f - 32);
    float4 bv = *reinterpret_cast<const float4*>(adst + (size_t)d * 8);
    int jb = off[d], je = off[d + 1];
    float acc = 0.f, ds = 0.f;
    for (int c0 = jb; c0 < je; c0 += 64) {
        int cnt = je - c0; if (cnt > 64) cnt = 64;
        if (lane < cnt) {   // phase A: one lane per edge; bf16 scores
            int s = srt[c0 + lane];
            sS[wslot][lane] = s;
            uint2 sv = *reinterpret_cast<const uint2*>(&xcB[(size_t)s * 16 + 8]);
            float4 w;
            w.x = __expf(lrelu(bflo(sv.x) + bv.x));
            w.y = __expf(lrelu(bfhi(sv.x) + bv.y));
            w.z = __expf(lrelu(bflo(sv.y) + bv.z));
            w.w = __expf(lrelu(bfhi(sv.y) + bv.w));
            *reinterpret_cast<float4*>(&sW[wslot][lane * 4]) = w;
        }
        int j = 0;          // phase B: FMA loop (round-10 order)
        for (; j + 3 < cnt; j += 4) {
            int s0 = sS[wslot][j], s1 = sS[wslot][j + 1];
            int s2 = sS[wslot][j + 2], s3 = sS[wslot][j + 3];
            float w0 = sW[wslot][(j + 0) * 4 + hh];
            float w1 = sW[wslot][(j + 1) * 4 + hh];
            float w2 = sW[wslot][(j + 2) * 4 + hh];
            float w3 = sW[wslot][(j + 3) * 4 + hh];
            float x0 = __bfloat162float(xt[((size_t)s0 << sh) + fo]);
            float x1 = __bfloat162float(xt[((size_t)s1 << sh) + fo]);
            float x2 = __bfloat162float(xt[((size_t)s2 << sh) + fo]);
            float x3 = __bfloat162float(xt[((size_t)s3 << sh) + fo]);
            acc += w0 * x0; acc += w1 * x1; acc += w2 * x2; acc += w3 * x3;
            ds += (w0 + w1) + (w2 + w3);
        }
        for (; j < cnt; ++j) {
            int s = sS[wslot][j];
            float w = sW[wslot][j * 4 + hh];
            acc += w * __bfloat162float(xt[((size_t)s << sh) + fo]);
            ds += w;
        }
    }
    if (act) {
        float v = agg[(size_t)d * 40 + f] + acc / ds;
        agg[(size_t)d * 40 + f] = elu1(v);   // ELU fused (layers 1/2 only)
    }
}

// ---------------- CSR aggregation, H=6 -> bf16 z, fused weights (LDS) -------
// Round-10 structure, 2 lines/edge, phase B unrolled to 4 edges/round
// (4 hp gathers in flight -> half the dependent-latency rounds per node).
__global__ __launch_bounds__(256)
void z6_csr_kernel(const int* __restrict__ off, const int* __restrict__ srt,
                   const float* __restrict__ adst,
                   const __hip_bfloat16* __restrict__ hpA,
                   const __hip_bfloat16* __restrict__ hcB, __hip_bfloat16* zb) {
    __shared__ float sW[4][64 * 6];
    __shared__ int   sS[4][64];
    int t = threadIdx.x;
    int wslot = t >> 6;
    int wid = (blockIdx.x * 256 + t) >> 6;
    int d = __builtin_amdgcn_readfirstlane(wid);
    if (d >= NN) return;
    int lane = t & 63;
    bool act = lane < 40;
    int f = act ? lane : 0;
    const __hip_bfloat16* ht = (f < 32) ? hpA : hcB;
    const int sh = (f < 32) ? 5 : 4;
    const int fo = (f < 32) ? f : (f - 32);
    float4 bv0 = *reinterpret_cast<const float4*>(adst + (size_t)d * 8);
    float2 bv1 = *reinterpret_cast<const float2*>(adst + (size_t)d * 8 + 4);
    int jb = off[d], je = off[d + 1];
    float acc[6], ds[6];
#pragma unroll
    for (int h = 0; h < 6; h++) { acc[h] = 0.f; ds[h] = 0.f; }
    for (int c0 = jb; c0 < je; c0 += 64) {
        int cnt = je - c0; if (cnt > 64) cnt = 64;
        if (lane < cnt) {   // phase A: bf16 scores from the combined row
            int s = srt[c0 + lane];
            sS[wslot][lane] = s;
            uint4 sv = *reinterpret_cast<const uint4*>(&hcB[(size_t)s * 16 + 8]);
            float* wp = &sW[wslot][lane * 6];
            *reinterpret_cast<float4*>(wp) = make_float4(
                __expf(lrelu(bflo(sv.x) + bv0.x)), __expf(lrelu(bfhi(sv.x) + bv0.y)),
                __expf(lrelu(bflo(sv.y) + bv0.z)), __expf(lrelu(bfhi(sv.y) + bv0.w)));
            *reinterpret_cast<float2*>(wp + 4) = make_float2(
                __expf(lrelu(bflo(sv.z) + bv1.x)), __expf(lrelu(bfhi(sv.z) + bv1.y)));
        }
        int j = 0;          // phase B: 4-edge rounds (4 gathers in flight)
        for (; j + 3 < cnt; j += 4) {
            int s0 = sS[wslot][j],     s1 = sS[wslot][j + 1];
            int s2 = sS[wslot][j + 2], s3 = sS[wslot][j + 3];
            float hv0 = __bfloat162float(ht[((size_t)s0 << sh) + fo]);
            float hv1 = __bfloat162float(ht[((size_t)s1 << sh) + fo]);
            float hv2 = __bfloat162float(ht[((size_t)s2 << sh) + fo]);
            float hv3 = __bfloat162float(ht[((size_t)s3 << sh) + fo]);
            const float* wp = &sW[wslot][j * 6];
#pragma unroll
            for (int h = 0; h < 6; h++) {
                float w0 = wp[h], w1 = wp[6 + h], w2 = wp[12 + h], w3 = wp[18 + h];
                acc[h] += w0 * hv0; acc[h] += w1 * hv1;
                acc[h] += w2 * hv2; acc[h] += w3 * hv3;
                ds[h] += (w0 + w1) + (w2 + w3);
            }
        }
        for (; j + 1 < cnt; j += 2) {
            int s0 = sS[wslot][j], s1 = sS[wslot][j + 1];
            float hv0 = __bfloat162float(ht[((size_t)s0 << sh) + fo]);
            float hv1 = __bfloat162float(ht[((size_t)s1 << sh) + fo]);
            const float* wp = &sW[wslot][j * 6];
#pragma unroll
            for (int h = 0; h < 6; h++) {
                float w0 = wp[h], w1 = wp[6 + h];
                acc[h] += w0 * hv0; acc[h] += w1 * hv1;
                ds[h] += w0 + w1;
            }
        }
        for (; j < cnt; ++j) {
            int s = sS[wslot][j];
            float hv = __bfloat162float(ht[((size_t)s << sh) + fo]);
            const float* wp = &sW[wslot][j * 6];
#pragma unroll
            for (int h = 0; h < 6; h++) {
                acc[h] += wp[h] * hv;
                ds[h] += wp[h];
            }
        }
    }
    if (act) {
#pragma unroll
        for (int h = 0; h < 6; h++)
            zb[(size_t)d * 288 + h * 40 + f] =
                __float2bfloat16(acc[h] / ds[h] * (1.0f / 6.0f));
    }
}

// ---------------- MFMA GEMM: out[100000x121] = A[100000x288]@B[288x128] + bias
__global__ __launch_bounds__(256)
void zgemm_mfma_kernel(const __hip_bfloat16* __restrict__ Ab,
                       const __hip_bfloat16* __restrict__ Bf,
                       const float* __restrict__ b3, const float* __restrict__ lb3,
                       float* __restrict__ out) {
    const int t = threadIdx.x;
    const int lane = t & 63, w = t >> 6;
    const int wr = w & 1, wc = w >> 1;
    const int n0 = blockIdx.x * 128;
    const short* As = (const short*)Ab;
    const short* Bs = (const short*)Bf;

    f32x4 acc[4][4];
#pragma unroll
    for (int i = 0; i < 4; i++)
#pragma unroll
        for (int j = 0; j < 4; j++) acc[i][j] = (f32x4){0.f, 0.f, 0.f, 0.f};

    const int arow = n0 + wr * 64 + (lane & 15);
    const int koff = (lane >> 4) * 8;

    for (int kk = 0; kk < 9; kk++) {
        bf16x8 af[4], bfr[4];
#pragma unroll
        for (int i = 0; i < 4; i++) {
            int r = arow + i * 16; if (r > NN - 1) r = NN - 1;
            af[i] = *(const bf16x8*)(As + (size_t)r * 288 + kk * 32 + koff);
        }
#pragma unroll
        for (int j = 0; j < 4; j++) {
            int ct = wc * 4 + j;
            bfr[j] = *(const bf16x8*)(Bs + (((size_t)kk * 8 + ct) * 64 + lane) * 8);
        }
#pragma unroll
        for (int i = 0; i < 4; i++)
#pragma unroll
            for (int j = 0; j < 4; j++)
                acc[i][j] = __builtin_amdgcn_mfma_f32_16x16x32_bf16(af[i], bfr[j], acc[i][j], 0, 0, 0);
    }

    const int c_base = wc * 64 + (lane & 15);
    const int r_quad = (lane >> 4) * 4;
#pragma unroll
    for (int j = 0; j < 4; j++) {
        int c = c_base + j * 16;
        if (c >= COUT) continue;
        float bias = b3[c] + lb3[c];
#pragma unroll
        for (int i = 0; i < 4; i++) {
            int nb = n0 + wr * 64 + i * 16 + r_quad;
#pragma unroll
            for (int q = 0; q < 4; q++) {
                int n = nb + q;
                if (n < NN) out[(size_t)n * COUT + c] = acc[i][j][q] + bias;
            }
        }
    }
}

extern "C" void kernel_launch(void* const* d_in, const int* in_sizes, int n_in,
                              void* d_out, int out_size, void* d_ws, size_t ws_size,
                              hipStream_t stream) {
    const float* x   = (const float*)d_in[0];
    const int*   ei  = (const int*)d_in[1];
    const float* W1  = (const float*)d_in[2];
    const float* as1 = (const float*)d_in[3];
    const float* ad1 = (const float*)d_in[4];
    const float* b1  = (const float*)d_in[5];
    const float* lw1 = (const float*)d_in[6];
    const float* lb1 = (const float*)d_in[7];
    const float* W2  = (const float*)d_in[8];
    const float* as2 = (const float*)d_in[9];
    const float* ad2 = (const float*)d_in[10];
    const float* b2  = (const float*)d_in[11];
    const float* lw2 = (const float*)d_in[12];
    const float* lb2 = (const float*)d_in[13];
    const float* W3  = (const float*)d_in[14];
    const float* as3 = (const float*)d_in[15];
    const float* ad3 = (const float*)d_in[16];
    const float* b3  = (const float*)d_in[17];
    const float* lw3 = (const float*)d_in[18];
    const float* lb3 = (const float*)d_in[19];
    float* out = (float*)d_out;
    float* ws  = (float*)d_ws;

    const int* esrc = ei;
    const int* edst = ei + NE;

    // ---- workspace layout (floats unless noted) ----
    // [0, 1.6M)      xbA (bf16) | hpA (bf16, layer 3) - same slot
    // [1.6M, 2.4M)   xcB (bf16, 100000x16) | hcB      - same slot
    // [4M, 8M)       agg
    // [8.8M, 9.6M)   adst ; [9.6M,...) Bc, Bf
    // [9.628M, 24.028M) zb (bf16)
    // [24.028M, ...) CSR ints
    __hip_bfloat16* xbA = (__hip_bfloat16*)ws;
    __hip_bfloat16* xcB = (__hip_bfloat16*)(ws + 1600000);
    float* agg  = ws + 4000000;
    float* adst = ws + 8800000;
    float* Bc   = ws + 9600000;
    __hip_bfloat16* Bf = (__hip_bfloat16*)(ws + 9608000);
    __hip_bfloat16* zb = (__hip_bfloat16*)(ws + 9628000);
    __hip_bfloat16* hpA = xbA;   // layer 3 reuses the same slots
    __hip_bfloat16* hcB = xcB;
    int* ib     = (int*)(ws + 24028000);
    int* deg    = ib;                 // 100,352
    int* off    = ib + 100352;        // 100,001 (+pad)
    int* bcnt   = ib + 200704;        // 128
    int* boff   = ib + 200832;        // 129
    int* bcur   = ib + 200992;        // 128
    int* bsum   = ib + 300704;        // 512
    int* bscan  = ib + 301216;        // 512
    int* sorted = ib + 301728;        // 1,700,000 -> ends 2,001,728
    int* ebuf   = ib + 2001728;       // 1,600,000 -> ends 3,601,728

    const int nodeBlocks = (NN + 255) / 256;       // 391
    const int binBlocks  = (NE + EPB - 1) / EPB;   // 196
    const int waveBlocks = NN / 4;                 // 25000
    const int featBlocks = (NN + 63) / 64;         // 1563 (64 rows/block)

    // ---- bucketed CSR build ----
    zero_bcnt_kernel<<<1, 256, 0, stream>>>(bcnt);
    bin_count_kernel<<<binBlocks, 256, 0, stream>>>(edst, bcnt);
    bin_scan_kernel<<<1, 256, 0, stream>>>(bcnt, boff, bcur);
    bin_place_kernel<<<binBlocks, 256, 0, stream>>>(esrc, edst, bcur, ebuf);
    bucket_deg_kernel<<<NB, 256, 0, stream>>>(boff, ebuf, deg);
    scan_block_kernel<<<nodeBlocks, 256, 0, stream>>>(deg, off, bsum);
    scan_bsum_kernel<<<1, 256, 0, stream>>>(bsum, bscan, nodeBlocks);
    place_kernel<<<nodeBlocks, 256, 0, stream>>>(off, bscan, sorted);
    bucket_scatter_kernel<<<NB, 256, 0, stream>>>(boff, ebuf, off, sorted);

    // ---- layer 1 ----
    fold_B12_kernel<<<(FIN * 88 + 255) / 256, 256, 0, stream>>>(W1, lw1, as1, ad1, Bc, FIN);
    feature12_kernel<FIN><<<featBlocks, 256, 0, stream>>>(x, Bc, b1, lb1, xbA, xcB, agg, adst);
    agg4_csr_kernel<<<waveBlocks, 256, 0, stream>>>(off, sorted, adst, xbA, xcB, agg);

    // ---- layer 2 ----
    fold_B12_kernel<<<(HID * 88 + 255) / 256, 256, 0, stream>>>(W2, lw2, as2, ad2, Bc, HID);
    feature12_kernel<HID><<<featBlocks, 256, 0, stream>>>(agg, Bc, b2, lb2, xbA, xcB, agg, adst);
    agg4_csr_kernel<<<waveBlocks, 256, 0, stream>>>(off, sorted, adst, xbA, xcB, agg);

    // ---- layer 3 ----
    fold_B3_kernel<<<(40 * 12 + 255) / 256, 256, 0, stream>>>(W3, as3, ad3, Bc);
    fold_Bf_kernel<<<(9 * 8 * 64 * 8 + 255) / 256, 256, 0, stream>>>(W3, lw3, Bf);
    feature3_kernel<<<nodeBlocks, 256, 0, stream>>>(agg, Bc, adst, zb, hpA, hcB);
    z6_csr_kernel<<<waveBlocks, 256, 0, stream>>>(off, sorted, adst, hpA, hcB, zb);
    zgemm_mfma_kernel<<<(NN + 127) / 128, 256, 0, stream>>>(zb, Bf, b3, lb3, out);
}